// Round 10
// baseline (533.665 us; speedup 1.0000x reference)
//
#include <hip/hip_runtime.h>
#include <hip/hip_bf16.h>

constexpr int NN   = 100000;
constexpr int EE   = 1600000;
constexpr int ETOT = EE + NN;
constexpr float SLOPE = 0.2f;
constexpr int BSH = 8;      // nodes per bucket = 256
constexpr int NB  = (NN + (1 << BSH) - 1) >> BSH;  // 391 buckets
constexpr int CCH = 8192;   // edges per scatter block
constexpr int DCAP  = 36;   // per-node edge cap for packed path
constexpr int DCAPP = 37;   // padded stride -> phase-B reads conflict-free
constexpr int LDKB  = 136;  // B LDS stride: 128 + 8 pad
constexpr int XB_BLOCKS = (NN * 64 / 8) / 256;     // 3125 exact
constexpr int WB_BLOCKS = 176;
constexpr int BH_BLOCKS = (EE + 2047) / 2048;      // 782 bhist chunks
constexpr int GBLK = (NN + 127) / 128;             // 782 GEMM tiles
constexpr int NHALF = 50000;                       // aggregate split point (visibility round)

typedef __attribute__((ext_vector_type(8))) short short8;
typedef __attribute__((ext_vector_type(4))) float f32x4;

__device__ __forceinline__ float bf_lo(unsigned u) { return __uint_as_float(u << 16); }
__device__ __forceinline__ float bf_hi(unsigned u) { return __uint_as_float(u & 0xffff0000u); }
__device__ __forceinline__ unsigned short f2bf(float f) {
    __hip_bfloat16 h = __float2bfloat16(f);
    return *(unsigned short*)&h;
}
__device__ __forceinline__ void wave_lds_fence() {
    __asm__ volatile("s_waitcnt lgkmcnt(0)" ::: "memory");
}
__device__ __forceinline__ void fma8(float* acc, uint4 u, float al) {
    acc[0] += bf_lo(u.x) * al; acc[1] += bf_hi(u.x) * al;
    acc[2] += bf_lo(u.y) * al; acc[3] += bf_hi(u.y) * al;
    acc[4] += bf_lo(u.z) * al; acc[5] += bf_hi(u.z) * al;
    acc[6] += bf_lo(u.w) * al; acc[7] += bf_hi(u.w) * al;
}
__device__ __forceinline__ void fma4(float* acc, uint2 u, float al) {
    acc[0] += bf_lo(u.x) * al; acc[1] += bf_hi(u.x) * al;
    acc[2] += bf_lo(u.y) * al; acc[3] += bf_hi(u.y) * al;
}

// ---- fused prep: x->bf16, all W->bf16^T, and bucket histogram (gbh pre-zeroed
// by hipMemsetAsync on the same stream) ----
__global__ __launch_bounds__(256) void k_prep(
    const float* __restrict__ x, unsigned short* __restrict__ xb,
    const float* __restrict__ W0, const float* __restrict__ W1,
    const float* __restrict__ W2, const float* __restrict__ Wf,
    unsigned short* __restrict__ Wt0, unsigned short* __restrict__ Wt1,
    unsigned short* __restrict__ Wt2, unsigned short* __restrict__ Wtf,
    int* __restrict__ gbh, const int* __restrict__ ei) {
    int b = blockIdx.x, t = threadIdx.x;
    if (b < XB_BLOCKS) {
        int i = b * 256 + t;
        const float4* xp = (const float4*)(x + (size_t)i * 8);
        float4 v0 = xp[0], v1 = xp[1];
        unsigned short o[8] = {f2bf(v0.x), f2bf(v0.y), f2bf(v0.z), f2bf(v0.w),
                               f2bf(v1.x), f2bf(v1.y), f2bf(v1.z), f2bf(v1.w)};
        *(uint4*)(xb + (size_t)i * 8) = *(uint4*)o;
    } else if (b < XB_BLOCKS + WB_BLOCKS) {
        int i = (b - XB_BLOCKS) * 256 + t;
        if (i < 8192) {                       // W0: 64x128
            int k = i / 128, n = i % 128;
            Wt0[n * 64 + k] = f2bf(W0[i]);
        } else if (i < 24576) {               // W1: 128x128
            int j = i - 8192; int k = j / 128, n = j % 128;
            Wt1[n * 128 + k] = f2bf(W1[j]);
        } else if (i < 40960) {               // W2: 128x128
            int j = i - 24576; int k = j / 128, n = j % 128;
            Wt2[n * 128 + k] = f2bf(W2[j]);
        } else if (i < 45056) {               // Wf: 128x32
            int j = i - 40960; int k = j / 32, n = j % 32;
            Wtf[n * 128 + k] = f2bf(Wf[j]);
        }
    } else {
        // bucket histogram chunk (was k_bhist)
        __shared__ int h[NB];
        for (int i = t; i < NB; i += 256) h[i] = 0;
        __syncthreads();
        int i = (b - XB_BLOCKS - WB_BLOCKS) * 2048 + t;
#pragma unroll
        for (int k = 0; k < 8; k++, i += 256)
            if (i < EE) atomicAdd(&h[ei[EE + i] >> BSH], 1);
        __syncthreads();
        for (int j = t; j < NB; j += 256)
            if (h[j]) atomicAdd(&gbh[j], h[j]);
    }
}

// ---------------- bucketed CSR build (R7-verified) ----------------
__global__ void k_bscan(const int* __restrict__ gbh, int* __restrict__ ebase,
                        int* __restrict__ gcur) {
    __shared__ int sd[512];
    int t = threadIdx.x;   // 512 threads
    int v = (t < NB) ? gbh[t] : 0;
    sd[t] = v;
    __syncthreads();
    for (int off = 1; off < 512; off <<= 1) {
        int x = (t >= off) ? sd[t - off] : 0;
        __syncthreads();
        sd[t] += x;
        __syncthreads();
    }
    int ex = sd[t] - v;
    if (t < NB) { ebase[t] = ex; gcur[t] = ex; }
    if (t == NB) ebase[NB] = EE;
}

__global__ __launch_bounds__(256) void k_bscatter(const int* __restrict__ ei,
                                                  int* __restrict__ gcur,
                                                  int* __restrict__ pbuf) {
    __shared__ int h[NB], base[NB], cur[NB];
    int t = threadIdx.x;
    for (int i = t; i < NB; i += 256) { h[i] = 0; cur[i] = 0; }
    __syncthreads();
    int c0 = blockIdx.x * CCH;
    int cend = c0 + CCH < EE ? c0 + CCH : EE;
    for (int i = c0 + t; i < cend; i += 256)
        atomicAdd(&h[ei[EE + i] >> BSH], 1);
    __syncthreads();
    for (int i = t; i < NB; i += 256)
        if (h[i] > 0) base[i] = atomicAdd(&gcur[i], h[i]);
    __syncthreads();
    for (int i = c0 + t; i < cend; i += 256) {
        int s = ei[i], d = ei[EE + i];
        int b = d >> BSH;
        int c = atomicAdd(&cur[b], 1);
        pbuf[base[b] + c] = s | ((d & ((1 << BSH) - 1)) << 17);
    }
}

__global__ __launch_bounds__(256) void k_bcsr(const int* __restrict__ pbuf,
                                              const int* __restrict__ ebase,
                                              int* __restrict__ row_ptr,
                                              int* __restrict__ esrc) {
    constexpr int BNODES = 1 << BSH;
    __shared__ int hist[BNODES];
    __shared__ int cur[BNODES];
    __shared__ int sd[256];
    int b = blockIdx.x, t = threadIdx.x;
    int node0 = b << BSH;
    int e0 = ebase[b], e1 = ebase[b + 1];
    hist[t] = 0; cur[t] = 0;
    __syncthreads();
    for (int i = e0 + t; i < e1; i += 256)
        atomicAdd(&hist[pbuf[i] >> 17], 1);
    __syncthreads();
    int ts = hist[t];
    sd[t] = ts;
    __syncthreads();
    for (int off = 1; off < 256; off <<= 1) {
        int x = (t >= off) ? sd[t - off] : 0;
        __syncthreads();
        sd[t] += x;
        __syncthreads();
    }
    int ex = sd[t] - ts;
    __syncthreads();
    hist[t] = ex;
    __syncthreads();
    int rbase = e0 + node0;
    int n = node0 + t;
    if (n < NN) {
        int rp = rbase + hist[t] + t;
        row_ptr[n] = rp;
        esrc[rp] = n;  // self loop in slot 0
    }
    __syncthreads();
    for (int i = e0 + t; i < e1; i += 256) {
        int p = pbuf[i];
        int nl = p >> 17;
        int c = atomicAdd(&cur[nl], 1);
        esrc[rbase + hist[nl] + nl + 1 + c] = p & 0x1FFFF;
    }
}

// ------- GEMM tile body (R6-verified): B pre-staged in LDS, A direct global->VGPR -------
template <int BN, int H>
__device__ __forceinline__ void gemm_tile(
    int rowBase, const unsigned short* __restrict__ Ab,
    const unsigned short* Bs, const float* __restrict__ as_,
    const float* __restrict__ ad_, unsigned short* __restrict__ hb,
    float* __restrict__ a_s, float* __restrict__ a_d, int M, int K) {
    constexpr int NCT = BN / 16;
    int tid = threadIdx.x;
    int lane = tid & 63, w = tid >> 6;
    int q = lane >> 4, col = lane & 15;

    f32x4 acc[2][NCT];
#pragma unroll
    for (int rt = 0; rt < 2; rt++)
#pragma unroll
        for (int ct = 0; ct < NCT; ct++) acc[rt][ct] = (f32x4){0.f, 0.f, 0.f, 0.f};

    int r0 = rowBase + w * 32 + col;
    int grc0 = min(r0, M - 1);
    int grc1 = min(r0 + 16, M - 1);
    const unsigned short* a0p = Ab + (size_t)grc0 * K + q * 8;
    const unsigned short* a1p = Ab + (size_t)grc1 * K + q * 8;

    int nph = K >> 6;
    for (int ph = 0; ph < nph; ph++) {
        int kof = ph * 64;
        short8 af[2][2];
        af[0][0] = *(const short8*)(a0p + kof);
        af[0][1] = *(const short8*)(a0p + kof + 32);
        af[1][0] = *(const short8*)(a1p + kof);
        af[1][1] = *(const short8*)(a1p + kof + 32);
#pragma unroll
        for (int kt = 0; kt < 2; kt++)
#pragma unroll
            for (int ct = 0; ct < NCT; ct++) {
                short8 bf = *(const short8*)(&Bs[(ct * 16 + col) * LDKB + kof + kt * 32 + q * 8]);
#pragma unroll
                for (int rt = 0; rt < 2; rt++)
                    acc[rt][ct] = __builtin_amdgcn_mfma_f32_16x16x32_bf16(
                        af[rt][kt], bf, acc[rt][ct], 0, 0, 0);
            }
    }

    float swv[NCT], dwv[NCT];
#pragma unroll
    for (int ct = 0; ct < NCT; ct++) {
        int c = ct * 16 + col;
        swv[ct] = as_[c];
        dwv[ct] = ad_[c];
    }
#pragma unroll
    for (int rt = 0; rt < 2; rt++) {
#pragma unroll
        for (int r = 0; r < 4; r++) {
            int gr = rowBase + w * 32 + rt * 16 + q * 4 + r;
            if constexpr (H == 4) {
                float ps[4] = {0, 0, 0, 0}, pd[4] = {0, 0, 0, 0};
#pragma unroll
                for (int ct = 0; ct < NCT; ct++) {
                    float v = acc[rt][ct][r];
                    ps[ct >> 1] += v * swv[ct];
                    pd[ct >> 1] += v * dwv[ct];
                }
#pragma unroll
                for (int m = 1; m < 16; m <<= 1)
#pragma unroll
                    for (int h = 0; h < 4; h++) {
                        ps[h] += __shfl_xor(ps[h], m);
                        pd[h] += __shfl_xor(pd[h], m);
                    }
                if (gr < M) {
#pragma unroll
                    for (int ct = 0; ct < NCT; ct++)
                        hb[(size_t)gr * BN + ct * 16 + col] = f2bf(acc[rt][ct][r]);
                    if (col == 0) {
                        *(float4*)(a_s + (size_t)gr * 4) = make_float4(ps[0], ps[1], ps[2], ps[3]);
                        *(float4*)(a_d + (size_t)gr * 4) = make_float4(pd[0], pd[1], pd[2], pd[3]);
                    }
                }
            } else {
                float ps = 0.f, pd = 0.f;
#pragma unroll
                for (int ct = 0; ct < NCT; ct++) {
                    float v = acc[rt][ct][r];
                    ps += v * swv[ct];
                    pd += v * dwv[ct];
                }
#pragma unroll
                for (int m = 1; m < 16; m <<= 1) {
                    ps += __shfl_xor(ps, m);
                    pd += __shfl_xor(pd, m);
                }
                if (gr < M) {
#pragma unroll
                    for (int ct = 0; ct < NCT; ct++)
                        hb[(size_t)gr * BN + ct * 16 + col] = f2bf(acc[rt][ct][r]);
                    if (col == 0) { a_s[gr] = ps; a_d[gr] = pd; }
                }
            }
        }
    }
}

// B staging into LDS (stride LDKB), whole Wt (BN x K)
template <int BN>
__device__ __forceinline__ void stage_B(unsigned short* Bs,
                                        const unsigned short* __restrict__ Bt, int K) {
    int tid = threadIdx.x;
    int kvs = (K == 64) ? 3 : 4;
    for (int idx = tid; idx < (BN << kvs); idx += 256) {
        int br = idx >> kvs;
        int ko = (idx & ((1 << kvs) - 1)) << 3;
        *(uint4*)(&Bs[br * LDKB + ko]) = *(const uint4*)(Bt + (size_t)br * K + ko);
    }
}

template <int BN, int H>
__global__ __launch_bounds__(256) void k_mfma_att(
    const unsigned short* __restrict__ Ab, const unsigned short* __restrict__ Bt,
    const float* __restrict__ as_, const float* __restrict__ ad_,
    unsigned short* __restrict__ hb, float* __restrict__ a_s,
    float* __restrict__ a_d, int M, int K) {
    __shared__ unsigned short Bs[128 * LDKB];
    stage_B<BN>(Bs, Bt, K);
    __syncthreads();
    gemm_tile<BN, H>(blockIdx.x * 128, Ab, Bs, as_, ad_, hb, a_s, a_d, M, K);
}

// -------- 4-nodes-per-wave aggregate (R2-verified body); n_base for range split --------
__global__ __launch_bounds__(128) void k_aggregate_ln(
    int n_base,
    const unsigned short* __restrict__ hb, const float* __restrict__ a_src,
    const float* __restrict__ a_dst, const int* __restrict__ row_ptr,
    const int* __restrict__ esrc, const float* __restrict__ bias,
    const float* __restrict__ gamma, const float* __restrict__ beta,
    unsigned short* __restrict__ xb) {
    __shared__ uint2 slab_all[2][4 * 4 * DCAPP];
    int tid = threadIdx.x;
    int w = tid >> 6, lane = tid & 63;
    int g = lane >> 4, i = lane & 15;
    int myhead = i >> 2;
    uint2* slab = slab_all[w];
    int n0 = n_base + blockIdx.x * 8 + w * 4;
    int n = n0 + g;
    bool valid = n < NN;
    int start = 0, deg = 0;
    if (valid) {
        start = row_ptr[n];
        int end = (n == NN - 1) ? ETOT : row_ptr[n + 1];
        deg = end - start;
    }
    int wmax = deg;
#pragma unroll
    for (int m = 1; m < 64; m <<= 1) wmax = max(wmax, __shfl_xor(wmax, m));

    if (wmax <= DCAP) {
        float4 ad = make_float4(0.f, 0.f, 0.f, 0.f);
        if (valid) ad = ((const float4*)a_dst)[n];
        float d0 = 0.f, d1 = 0.f, d2 = 0.f, d3 = 0.f;
        uint2* nslab = slab + g * (4 * DCAPP);
        for (int k = i; k < deg; k += 16) {
            int s = esrc[start + k];
            float4 a = ((const float4*)a_src)[s];
            float e0 = a.x + ad.x; e0 = fmaxf(e0, SLOPE * e0); float x0 = __expf(e0);
            float e1 = a.y + ad.y; e1 = fmaxf(e1, SLOPE * e1); float x1 = __expf(e1);
            float e2 = a.z + ad.z; e2 = fmaxf(e2, SLOPE * e2); float x2 = __expf(e2);
            float e3 = a.w + ad.w; e3 = fmaxf(e3, SLOPE * e3); float x3 = __expf(e3);
            nslab[0 * DCAPP + k] = make_uint2((unsigned)s, __float_as_uint(x0));
            nslab[1 * DCAPP + k] = make_uint2((unsigned)s, __float_as_uint(x1));
            nslab[2 * DCAPP + k] = make_uint2((unsigned)s, __float_as_uint(x2));
            nslab[3 * DCAPP + k] = make_uint2((unsigned)s, __float_as_uint(x3));
            d0 += x0; d1 += x1; d2 += x2; d3 += x3;
        }
#pragma unroll
        for (int m = 1; m < 16; m <<= 1) {
            d0 += __shfl_xor(d0, m);
            d1 += __shfl_xor(d1, m);
            d2 += __shfl_xor(d2, m);
            d3 += __shfl_xor(d3, m);
        }
        float dh = myhead == 0 ? d0 : myhead == 1 ? d1 : myhead == 2 ? d2 : d3;
        float inv = 1.f / (dh + 1e-16f);
        wave_lds_fence();

        float acc[8];
#pragma unroll
        for (int k = 0; k < 8; k++) acc[k] = 0.f;
        const uint2* myrow = nslab + myhead * DCAPP;
        const unsigned short* hbase = hb + i * 8;
        int j = 0;
        for (; j + 4 <= deg; j += 4) {
            uint2 p0 = myrow[j], p1 = myrow[j + 1], p2 = myrow[j + 2], p3 = myrow[j + 3];
            uint4 u0 = *(const uint4*)(hbase + (size_t)p0.x * 128);
            uint4 u1 = *(const uint4*)(hbase + (size_t)p1.x * 128);
            uint4 u2 = *(const uint4*)(hbase + (size_t)p2.x * 128);
            uint4 u3 = *(const uint4*)(hbase + (size_t)p3.x * 128);
            fma8(acc, u0, __uint_as_float(p0.y));
            fma8(acc, u1, __uint_as_float(p1.y));
            fma8(acc, u2, __uint_as_float(p2.y));
            fma8(acc, u3, __uint_as_float(p3.y));
        }
        for (; j < deg; j++) {
            uint2 p = myrow[j];
            uint4 uu = *(const uint4*)(hbase + (size_t)p.x * 128);
            fma8(acc, uu, __uint_as_float(p.y));
        }
#pragma unroll
        for (int k = 0; k < 8; k++) acc[k] *= inv;

        if (valid) {
            float y[8];
            float sum = 0.f;
            const float4* bp = (const float4*)(bias + i * 8);
            float4 b0 = bp[0], b1 = bp[1];
#pragma unroll
            for (int k = 0; k < 8; k++) {
                float b = k < 4 ? (&b0.x)[k] : (&b1.x)[k - 4];
                y[k] = acc[k] + b;
                sum += y[k];
            }
#pragma unroll
            for (int m = 1; m < 16; m <<= 1) sum += __shfl_xor(sum, m);
            float mu = sum * (1.f / 128.f);
            float ss = 0.f;
            float d[8];
#pragma unroll
            for (int k = 0; k < 8; k++) { d[k] = y[k] - mu; ss += d[k] * d[k]; }
#pragma unroll
            for (int m = 1; m < 16; m <<= 1) ss += __shfl_xor(ss, m);
            float is = rsqrtf(ss * (1.f / 128.f) + 1e-5f);
            const float4* gp = (const float4*)(gamma + i * 8);
            const float4* ep = (const float4*)(beta + i * 8);
            float4 g0 = gp[0], g1 = gp[1], e0 = ep[0], e1 = ep[1];
            unsigned short o16[8];
#pragma unroll
            for (int k = 0; k < 8; k++) {
                float gm = k < 4 ? (&g0.x)[k] : (&g1.x)[k - 4];
                float bt = k < 4 ? (&e0.x)[k] : (&e1.x)[k - 4];
                float z = gm * (d[k] * is) + bt;
                o16[k] = f2bf(z > 0.f ? z : __expf(z) - 1.f);
            }
            *(uint4*)(xb + (size_t)n * 128 + i * 8) = *(uint4*)o16;
        }
    } else {
        // cold path (~never): wave's 4 nodes sequentially, full-wave.
        for (int m4 = 0; m4 < 4; m4++) {
            int nm = n0 + m4;
            if (nm >= NN) continue;
            int startm = row_ptr[nm];
            int endm = (nm == NN - 1) ? ETOT : row_ptr[nm + 1];
            int degm = endm - startm;
            float4 ad = ((const float4*)a_dst)[nm];
            int gg = lane >> 4, c16 = lane & 15, hh = c16 >> 2;
            float acc[8];
#pragma unroll
            for (int k = 0; k < 8; k++) acc[k] = 0.f;
            if (degm <= 64) {
                int msrc = 0;
                float me0 = 0.f, me1 = 0.f, me2 = 0.f, me3 = 0.f;
                if (lane < degm) {
                    int s = esrc[startm + lane];
                    msrc = s;
                    float4 a = ((const float4*)a_src)[s];
                    float e0 = a.x + ad.x; e0 = fmaxf(e0, SLOPE * e0); me0 = __expf(e0);
                    float e1 = a.y + ad.y; e1 = fmaxf(e1, SLOPE * e1); me1 = __expf(e1);
                    float e2 = a.z + ad.z; e2 = fmaxf(e2, SLOPE * e2); me2 = __expf(e2);
                    float e3 = a.w + ad.w; e3 = fmaxf(e3, SLOPE * e3); me3 = __expf(e3);
                }
                float d0 = me0, d1 = me1, d2 = me2, d3 = me3;
#pragma unroll
                for (int m = 1; m < 64; m <<= 1) {
                    d0 += __shfl_xor(d0, m);
                    d1 += __shfl_xor(d1, m);
                    d2 += __shfl_xor(d2, m);
                    d3 += __shfl_xor(d3, m);
                }
                me0 *= 1.f / (d0 + 1e-16f);
                me1 *= 1.f / (d1 + 1e-16f);
                me2 *= 1.f / (d2 + 1e-16f);
                me3 *= 1.f / (d3 + 1e-16f);
                int iters = (degm + 3) >> 2;
                for (int it = 0; it < iters; it++) {
                    int j = gg + (it << 2);
                    int jj = j < degm ? j : 0;
                    int s = __shfl(msrc, jj);
                    float a0 = __shfl(me0, jj), a1 = __shfl(me1, jj);
                    float a2 = __shfl(me2, jj), a3 = __shfl(me3, jj);
                    if (j < degm) {
                        float al = hh == 0 ? a0 : hh == 1 ? a1 : hh == 2 ? a2 : a3;
                        uint4 uu = *(const uint4*)(hb + (size_t)s * 128 + c16 * 8);
                        fma8(acc, uu, al);
                    }
                }
            } else {
                float d0 = 0.f, d1 = 0.f, d2 = 0.f, d3 = 0.f;
                for (int k = startm + lane; k < endm; k += 64) {
                    int s = esrc[k];
                    float4 a = ((const float4*)a_src)[s];
                    float e0 = a.x + ad.x; e0 = fmaxf(e0, SLOPE * e0); d0 += __expf(e0);
                    float e1 = a.y + ad.y; e1 = fmaxf(e1, SLOPE * e1); d1 += __expf(e1);
                    float e2 = a.z + ad.z; e2 = fmaxf(e2, SLOPE * e2); d2 += __expf(e2);
                    float e3 = a.w + ad.w; e3 = fmaxf(e3, SLOPE * e3); d3 += __expf(e3);
                }
#pragma unroll
                for (int m = 1; m < 64; m <<= 1) {
                    d0 += __shfl_xor(d0, m);
                    d1 += __shfl_xor(d1, m);
                    d2 += __shfl_xor(d2, m);
                    d3 += __shfl_xor(d3, m);
                }
                float invh = hh == 0 ? 1.f / (d0 + 1e-16f) : hh == 1 ? 1.f / (d1 + 1e-16f)
                           : hh == 2 ? 1.f / (d2 + 1e-16f) : 1.f / (d3 + 1e-16f);
                float adh = hh == 0 ? ad.x : hh == 1 ? ad.y : hh == 2 ? ad.z : ad.w;
                for (int j = gg; j < degm; j += 4) {
                    int s = esrc[startm + j];
                    float e = a_src[(size_t)s * 4 + hh] + adh;
                    e = fmaxf(e, SLOPE * e);
                    float al = __expf(e) * invh;
                    uint4 uu = *(const uint4*)(hb + (size_t)s * 128 + c16 * 8);
                    fma8(acc, uu, al);
                }
            }
#pragma unroll
            for (int k = 0; k < 8; k++) {
                acc[k] += __shfl_xor(acc[k], 16);
                acc[k] += __shfl_xor(acc[k], 32);
            }
            if (lane < 16) {
                float y[8];
                float sum = 0.f;
                const float4* bp = (const float4*)(bias + lane * 8);
                float4 b0 = bp[0], b1 = bp[1];
#pragma unroll
                for (int k = 0; k < 8; k++) {
                    float b = k < 4 ? (&b0.x)[k] : (&b1.x)[k - 4];
                    y[k] = acc[k] + b;
                    sum += y[k];
                }
#pragma unroll
                for (int m = 1; m < 16; m <<= 1) sum += __shfl_xor(sum, m);
                float mu = sum * (1.f / 128.f);
                float ss = 0.f;
                float d[8];
#pragma unroll
                for (int k = 0; k < 8; k++) { d[k] = y[k] - mu; ss += d[k] * d[k]; }
#pragma unroll
                for (int m = 1; m < 16; m <<= 1) ss += __shfl_xor(ss, m);
                float is = rsqrtf(ss * (1.f / 128.f) + 1e-5f);
                const float4* gp = (const float4*)(gamma + lane * 8);
                const float4* ep = (const float4*)(beta + lane * 8);
                float4 g0 = gp[0], g1 = gp[1], e0 = ep[0], e1 = ep[1];
                unsigned short o16[8];
#pragma unroll
                for (int k = 0; k < 8; k++) {
                    float gm = k < 4 ? (&g0.x)[k] : (&g1.x)[k - 4];
                    float bt = k < 4 ? (&e0.x)[k] : (&e1.x)[k - 4];
                    float z = gm * (d[k] * is) + bt;
                    o16[k] = f2bf(z > 0.f ? z : __expf(z) - 1.f);
                }
                *(uint4*)(xb + (size_t)nm * 128 + lane * 8) = *(uint4*)o16;
            }
        }
    }
}

// -------- final layer: 8-lane groups, 8 nodes/wave (R7-verified). H=1, C=32. --------
__global__ __launch_bounds__(128) void k_agg_final(
    const unsigned short* __restrict__ hb, const float* __restrict__ a_src,
    const float* __restrict__ a_dst, const int* __restrict__ row_ptr,
    const int* __restrict__ esrc, const float* __restrict__ bf,
    float* __restrict__ out) {
    __shared__ uint2 slab_all[2][8 * DCAPP];
    int tid = threadIdx.x;
    int w = tid >> 6, lane = tid & 63;
    int g = lane >> 3, i = lane & 7;
    uint2* nslab = slab_all[w] + g * DCAPP;
    int n0 = blockIdx.x * 16 + w * 8;
    int n = n0 + g;
    bool valid = n < NN;
    int start = 0, deg = 0;
    if (valid) {
        start = row_ptr[n];
        int end = (n == NN - 1) ? ETOT : row_ptr[n + 1];
        deg = end - start;
    }
    int wmax = deg;
#pragma unroll
    for (int m = 1; m < 64; m <<= 1) wmax = max(wmax, __shfl_xor(wmax, m));

    if (wmax <= DCAP) {
        float adn = valid ? a_dst[n] : 0.f;
        float d = 0.f;
        for (int k = i; k < deg; k += 8) {
            int s = esrc[start + k];
            float e = a_src[s] + adn;
            e = fmaxf(e, SLOPE * e);
            float xv = __expf(e);
            nslab[k] = make_uint2((unsigned)s, __float_as_uint(xv));
            d += xv;
        }
#pragma unroll
        for (int m = 1; m < 8; m <<= 1) d += __shfl_xor(d, m);
        float inv = 1.f / (d + 1e-16f);
        wave_lds_fence();

        float acc[4] = {0.f, 0.f, 0.f, 0.f};
        const unsigned short* hbase = hb + i * 4;
        int j = 0;
        for (; j + 2 <= deg; j += 2) {
            uint2 p0 = nslab[j], p1 = nslab[j + 1];
            uint2 u0 = *(const uint2*)(hbase + (size_t)p0.x * 32);
            uint2 u1 = *(const uint2*)(hbase + (size_t)p1.x * 32);
            fma4(acc, u0, __uint_as_float(p0.y));
            fma4(acc, u1, __uint_as_float(p1.y));
        }
        if (j < deg) {
            uint2 p = nslab[j];
            uint2 u = *(const uint2*)(hbase + (size_t)p.x * 32);
            fma4(acc, u, __uint_as_float(p.y));
        }
        if (valid) {
            float4 b4 = ((const float4*)bf)[i];
            float4 o = make_float4(acc[0] * inv + b4.x, acc[1] * inv + b4.y,
                                   acc[2] * inv + b4.z, acc[3] * inv + b4.w);
            ((float4*)out)[(size_t)n * 8 + i] = o;
        }
    } else {
        for (int m8 = 0; m8 < 8; m8++) {
            int nm = n0 + m8;
            if (nm >= NN) continue;
            int startm = row_ptr[nm];
            int endm = (nm == NN - 1) ? ETOT : row_ptr[nm + 1];
            int degm = endm - startm;
            float adn = a_dst[nm];
            int gg = lane >> 3, c8 = lane & 7;
            float d = 0.f;
            for (int k = startm + lane; k < endm; k += 64) {
                int s = esrc[k];
                float e = a_src[s] + adn;
                e = fmaxf(e, SLOPE * e);
                d += __expf(e);
            }
#pragma unroll
            for (int m = 1; m < 64; m <<= 1) d += __shfl_xor(d, m);
            float inv = 1.f / (d + 1e-16f);
            float acc[4] = {0.f, 0.f, 0.f, 0.f};
            for (int j = gg; j < degm; j += 8) {
                int s = esrc[startm + j];
                float e = a_src[s] + adn;
                e = fmaxf(e, SLOPE * e);
                float al = __expf(e) * inv;
                uint2 u = *(const uint2*)(hb + (size_t)s * 32 + c8 * 4);
                fma4(acc, u, al);
            }
#pragma unroll
            for (int k = 0; k < 4; k++) {
                acc[k] += __shfl_xor(acc[k], 8);
                acc[k] += __shfl_xor(acc[k], 16);
                acc[k] += __shfl_xor(acc[k], 32);
            }
            if (lane < 8) {
                float4 b4 = ((const float4*)bf)[lane];
                float4 o = make_float4(acc[0] + b4.x, acc[1] + b4.y, acc[2] + b4.z,
                                       acc[3] + b4.w);
                ((float4*)out)[(size_t)nm * 8 + lane] = o;
            }
        }
    }
}

// ---------------- launch ----------------
extern "C" void kernel_launch(void* const* d_in, const int* in_sizes, int n_in,
                              void* d_out, int out_size, void* d_ws,
                              size_t ws_size, hipStream_t stream) {
    const float* x  = (const float*)d_in[0];
    const int* ei   = (const int*)d_in[1];
    const float* W[3]  = {(const float*)d_in[2], (const float*)d_in[8],  (const float*)d_in[14]};
    const float* AS[3] = {(const float*)d_in[3], (const float*)d_in[9],  (const float*)d_in[15]};
    const float* AD[3] = {(const float*)d_in[4], (const float*)d_in[10], (const float*)d_in[16]};
    const float* Bb[3] = {(const float*)d_in[5], (const float*)d_in[11], (const float*)d_in[17]};
    const float* G[3]  = {(const float*)d_in[6], (const float*)d_in[12], (const float*)d_in[18]};
    const float* BE[3] = {(const float*)d_in[7], (const float*)d_in[13], (const float*)d_in[19]};
    const float* Wf  = (const float*)d_in[20];
    const float* asf = (const float*)d_in[21];
    const float* adf = (const float*)d_in[22];
    const float* bfp = (const float*)d_in[23];
    float* out = (float*)d_out;

    unsigned short* xb = (unsigned short*)d_ws;          // NN*128 bf16 (layer0 uses [NN][64])
    unsigned short* hb = xb + (size_t)NN * 128;          // NN*128 bf16
    float* a_s = (float*)(hb + (size_t)NN * 128);
    float* a_d = a_s + (size_t)NN * 4;
    int* row_ptr = (int*)(a_d + (size_t)NN * 4);
    int* esrc    = row_ptr + NN;
    int* gbh     = esrc + ETOT;
    int* ebase   = gbh + NB;
    int* gcur    = ebase + NB + 1;
    int* pbuf    = gcur + NB;                            // EE ints
    unsigned short* Wt0 = (unsigned short*)(pbuf + EE);  // 128*64
    unsigned short* Wt1 = Wt0 + 128 * 64;                // 128*128
    unsigned short* Wt2 = Wt1 + 128 * 128;               // 128*128
    unsigned short* Wtf = Wt2 + 128 * 128;               // 32*128

    // zero bucket histogram, then fused prep (x/W convert + bhist)
    hipMemsetAsync(gbh, 0, NB * sizeof(int), stream);
    k_prep<<<XB_BLOCKS + WB_BLOCKS + BH_BLOCKS, 256, 0, stream>>>(
        x, xb, W[0], W[1], W[2], Wf, Wt0, Wt1, Wt2, Wtf, gbh, ei);

    // CSR build
    k_bscan<<<1, 512, 0, stream>>>(gbh, ebase, gcur);
    k_bscatter<<<(EE + CCH - 1) / CCH, 256, 0, stream>>>(ei, gcur, pbuf);
    k_bcsr<<<NB, 256, 0, stream>>>(pbuf, ebase, row_ptr, esrc);

    // layers — aggregate split into two half-range dispatches (visibility round:
    // caps aggregate dispatch dur at ~37us so mid-tier kernels surface in top-5)
    const unsigned short* Wts[3] = {Wt0, Wt1, Wt2};
    int K = 64;
    for (int l = 0; l < 3; l++) {
        k_mfma_att<128, 4><<<GBLK, 256, 0, stream>>>(xb, Wts[l], AS[l], AD[l],
                                                     hb, a_s, a_d, NN, K);
        k_aggregate_ln<<<NHALF / 8, 128, 0, stream>>>(0, hb, a_s, a_d, row_ptr,
                                                      esrc, Bb[l], G[l], BE[l], xb);
        k_aggregate_ln<<<(NN - NHALF + 7) / 8, 128, 0, stream>>>(NHALF, hb, a_s, a_d,
                                                                 row_ptr, esrc, Bb[l],
                                                                 G[l], BE[l], xb);
        K = 128;
    }
    k_mfma_att<32, 1><<<GBLK, 256, 0, stream>>>(xb, Wtf, asf, adf, hb, a_s, a_d,
                                                NN, 128);
    k_agg_final<<<(NN + 15) / 16, 128, 0, stream>>>(hb, a_s, a_d, row_ptr, esrc,
                                                    bfp, out);
}

// Round 12
// 508.451 us; speedup vs baseline: 1.0496x; 1.0496x over previous
//
#include <hip/hip_runtime.h>
#include <hip/hip_bf16.h>

constexpr int NN   = 100000;
constexpr int EE   = 1600000;
constexpr int ETOT = EE + NN;
constexpr float SLOPE = 0.2f;
constexpr int BSH = 8;      // nodes per bucket = 256
constexpr int NB  = (NN + (1 << BSH) - 1) >> BSH;  // 391 buckets
constexpr int CCH = 8192;   // edges per scatter block
constexpr int DCAP  = 36;   // per-node edge cap for packed path
constexpr int DCAPP = 37;   // padded stride -> phase-B reads conflict-free
constexpr int LDKB  = 136;  // B LDS stride: 128 + 8 pad
constexpr int XB_BLOCKS = (NN * 64 / 8) / 256;     // 3125 exact
constexpr int WB_BLOCKS = 176;
constexpr int BH_BLOCKS = (EE + 2047) / 2048;      // 782 bhist chunks
constexpr int GBLK = (NN + 127) / 128;             // 782 GEMM tiles

typedef __attribute__((ext_vector_type(8))) short short8;
typedef __attribute__((ext_vector_type(4))) float f32x4;

__device__ __forceinline__ float bf_lo(unsigned u) { return __uint_as_float(u << 16); }
__device__ __forceinline__ float bf_hi(unsigned u) { return __uint_as_float(u & 0xffff0000u); }
__device__ __forceinline__ unsigned short f2bf(float f) {
    __hip_bfloat16 h = __float2bfloat16(f);
    return *(unsigned short*)&h;
}
__device__ __forceinline__ void wave_lds_fence() {
    __asm__ volatile("s_waitcnt lgkmcnt(0)" ::: "memory");
}
__device__ __forceinline__ void fma8(float* acc, uint4 u, float al) {
    acc[0] += bf_lo(u.x) * al; acc[1] += bf_hi(u.x) * al;
    acc[2] += bf_lo(u.y) * al; acc[3] += bf_hi(u.y) * al;
    acc[4] += bf_lo(u.z) * al; acc[5] += bf_hi(u.z) * al;
    acc[6] += bf_lo(u.w) * al; acc[7] += bf_hi(u.w) * al;
}
__device__ __forceinline__ void fma4(float* acc, uint2 u, float al) {
    acc[0] += bf_lo(u.x) * al; acc[1] += bf_hi(u.x) * al;
    acc[2] += bf_lo(u.y) * al; acc[3] += bf_hi(u.y) * al;
}

// ---- fused prep: x->bf16, all W->bf16^T, and bucket histogram (gbh pre-zeroed
// by hipMemsetAsync on the same stream) ----
__global__ __launch_bounds__(256) void k_prep(
    const float* __restrict__ x, unsigned short* __restrict__ xb,
    const float* __restrict__ W0, const float* __restrict__ W1,
    const float* __restrict__ W2, const float* __restrict__ Wf,
    unsigned short* __restrict__ Wt0, unsigned short* __restrict__ Wt1,
    unsigned short* __restrict__ Wt2, unsigned short* __restrict__ Wtf,
    int* __restrict__ gbh, const int* __restrict__ ei) {
    int b = blockIdx.x, t = threadIdx.x;
    if (b < XB_BLOCKS) {
        int i = b * 256 + t;
        const float4* xp = (const float4*)(x + (size_t)i * 8);
        float4 v0 = xp[0], v1 = xp[1];
        unsigned short o[8] = {f2bf(v0.x), f2bf(v0.y), f2bf(v0.z), f2bf(v0.w),
                               f2bf(v1.x), f2bf(v1.y), f2bf(v1.z), f2bf(v1.w)};
        *(uint4*)(xb + (size_t)i * 8) = *(uint4*)o;
    } else if (b < XB_BLOCKS + WB_BLOCKS) {
        int i = (b - XB_BLOCKS) * 256 + t;
        if (i < 8192) {                       // W0: 64x128
            int k = i / 128, n = i % 128;
            Wt0[n * 64 + k] = f2bf(W0[i]);
        } else if (i < 24576) {               // W1: 128x128
            int j = i - 8192; int k = j / 128, n = j % 128;
            Wt1[n * 128 + k] = f2bf(W1[j]);
        } else if (i < 40960) {               // W2: 128x128
            int j = i - 24576; int k = j / 128, n = j % 128;
            Wt2[n * 128 + k] = f2bf(W2[j]);
        } else if (i < 45056) {               // Wf: 128x32
            int j = i - 40960; int k = j / 32, n = j % 32;
            Wtf[n * 128 + k] = f2bf(Wf[j]);
        }
    } else {
        // bucket histogram chunk (was k_bhist)
        __shared__ int h[NB];
        for (int i = t; i < NB; i += 256) h[i] = 0;
        __syncthreads();
        int i = (b - XB_BLOCKS - WB_BLOCKS) * 2048 + t;
#pragma unroll
        for (int k = 0; k < 8; k++, i += 256)
            if (i < EE) atomicAdd(&h[ei[EE + i] >> BSH], 1);
        __syncthreads();
        for (int j = t; j < NB; j += 256)
            if (h[j]) atomicAdd(&gbh[j], h[j]);
    }
}

// ---------------- bucketed CSR build ----------------
// R11: k_bscan eliminated. Each block computes the 391-bucket inclusive scan of gbh
// redundantly in LDS (512-slot Hillis-Steele, 256 threads x 2 elems). gcur is
// zero-initialized by the same memset as gbh; pbuf base = exclusive_scan + atomic.
__global__ __launch_bounds__(256) void k_bscatter(const int* __restrict__ ei,
                                                  const int* __restrict__ gbh,
                                                  int* __restrict__ gcur,
                                                  int* __restrict__ pbuf) {
    __shared__ int h[NB], base[NB], cur[NB];
    __shared__ int sb[512];
    int t = threadIdx.x;
    for (int i = t; i < NB; i += 256) { h[i] = 0; cur[i] = 0; }
    sb[t] = (t < NB) ? gbh[t] : 0;
    sb[t + 256] = (t + 256 < NB) ? gbh[t + 256] : 0;
    __syncthreads();
    for (int off = 1; off < 512; off <<= 1) {
        int x0 = (t >= off) ? sb[t - off] : 0;
        int x1 = sb[t + 256 - off];
        __syncthreads();
        sb[t] += x0; sb[t + 256] += x1;
        __syncthreads();
    }
    // sb = inclusive scan; exclusive[i] = (i>0) ? sb[i-1] : 0
    int c0 = blockIdx.x * CCH;
    int cend = c0 + CCH < EE ? c0 + CCH : EE;
    for (int i = c0 + t; i < cend; i += 256)
        atomicAdd(&h[ei[EE + i] >> BSH], 1);
    __syncthreads();
    for (int i = t; i < NB; i += 256)
        if (h[i] > 0) base[i] = ((i > 0) ? sb[i - 1] : 0) + atomicAdd(&gcur[i], h[i]);
    __syncthreads();
    for (int i = c0 + t; i < cend; i += 256) {
        int s = ei[i], d = ei[EE + i];
        int b = d >> BSH;
        int c = atomicAdd(&cur[b], 1);
        pbuf[base[b] + c] = s | ((d & ((1 << BSH) - 1)) << 17);
    }
}

__global__ __launch_bounds__(256) void k_bcsr(const int* __restrict__ pbuf,
                                              const int* __restrict__ gbh,
                                              int* __restrict__ row_ptr,
                                              int* __restrict__ esrc) {
    constexpr int BNODES = 1 << BSH;
    __shared__ int hist[BNODES];
    __shared__ int cur[BNODES];
    __shared__ int sd[256];
    __shared__ int sb[512];
    int b = blockIdx.x, t = threadIdx.x;
    int node0 = b << BSH;
    hist[t] = 0; cur[t] = 0;
    sb[t] = (t < NB) ? gbh[t] : 0;
    sb[t + 256] = (t + 256 < NB) ? gbh[t + 256] : 0;
    __syncthreads();
    for (int off = 1; off < 512; off <<= 1) {
        int x0 = (t >= off) ? sb[t - off] : 0;
        int x1 = sb[t + 256 - off];
        __syncthreads();
        sb[t] += x0; sb[t + 256] += x1;
        __syncthreads();
    }
    int e0 = (b > 0) ? sb[b - 1] : 0;   // exclusive scan bounds for this bucket
    int e1 = sb[b];
    for (int i = e0 + t; i < e1; i += 256)
        atomicAdd(&hist[pbuf[i] >> 17], 1);
    __syncthreads();
    int ts = hist[t];
    sd[t] = ts;
    __syncthreads();
    for (int off = 1; off < 256; off <<= 1) {
        int x = (t >= off) ? sd[t - off] : 0;
        __syncthreads();
        sd[t] += x;
        __syncthreads();
    }
    int ex = sd[t] - ts;
    __syncthreads();
    hist[t] = ex;
    __syncthreads();
    int rbase = e0 + node0;
    int n = node0 + t;
    if (n < NN) {
        int rp = rbase + hist[t] + t;
        row_ptr[n] = rp;
        esrc[rp] = n;  // self loop in slot 0
    }
    __syncthreads();
    for (int i = e0 + t; i < e1; i += 256) {
        int p = pbuf[i];
        int nl = p >> 17;
        int c = atomicAdd(&cur[nl], 1);
        esrc[rbase + hist[nl] + nl + 1 + c] = p & 0x1FFFF;
    }
}

// ------- GEMM tile body (R6-verified): B pre-staged in LDS, A direct global->VGPR -------
template <int BN, int H>
__device__ __forceinline__ void gemm_tile(
    int rowBase, const unsigned short* __restrict__ Ab,
    const unsigned short* Bs, const float* __restrict__ as_,
    const float* __restrict__ ad_, unsigned short* __restrict__ hb,
    float* __restrict__ a_s, float* __restrict__ a_d, int M, int K) {
    constexpr int NCT = BN / 16;
    int tid = threadIdx.x;
    int lane = tid & 63, w = tid >> 6;
    int q = lane >> 4, col = lane & 15;

    f32x4 acc[2][NCT];
#pragma unroll
    for (int rt = 0; rt < 2; rt++)
#pragma unroll
        for (int ct = 0; ct < NCT; ct++) acc[rt][ct] = (f32x4){0.f, 0.f, 0.f, 0.f};

    int r0 = rowBase + w * 32 + col;
    int grc0 = min(r0, M - 1);
    int grc1 = min(r0 + 16, M - 1);
    const unsigned short* a0p = Ab + (size_t)grc0 * K + q * 8;
    const unsigned short* a1p = Ab + (size_t)grc1 * K + q * 8;

    int nph = K >> 6;
    for (int ph = 0; ph < nph; ph++) {
        int kof = ph * 64;
        short8 af[2][2];
        af[0][0] = *(const short8*)(a0p + kof);
        af[0][1] = *(const short8*)(a0p + kof + 32);
        af[1][0] = *(const short8*)(a1p + kof);
        af[1][1] = *(const short8*)(a1p + kof + 32);
#pragma unroll
        for (int kt = 0; kt < 2; kt++)
#pragma unroll
            for (int ct = 0; ct < NCT; ct++) {
                short8 bf = *(const short8*)(&Bs[(ct * 16 + col) * LDKB + kof + kt * 32 + q * 8]);
#pragma unroll
                for (int rt = 0; rt < 2; rt++)
                    acc[rt][ct] = __builtin_amdgcn_mfma_f32_16x16x32_bf16(
                        af[rt][kt], bf, acc[rt][ct], 0, 0, 0);
            }
    }

    float swv[NCT], dwv[NCT];
#pragma unroll
    for (int ct = 0; ct < NCT; ct++) {
        int c = ct * 16 + col;
        swv[ct] = as_[c];
        dwv[ct] = ad_[c];
    }
#pragma unroll
    for (int rt = 0; rt < 2; rt++) {
#pragma unroll
        for (int r = 0; r < 4; r++) {
            int gr = rowBase + w * 32 + rt * 16 + q * 4 + r;
            if constexpr (H == 4) {
                float ps[4] = {0, 0, 0, 0}, pd[4] = {0, 0, 0, 0};
#pragma unroll
                for (int ct = 0; ct < NCT; ct++) {
                    float v = acc[rt][ct][r];
                    ps[ct >> 1] += v * swv[ct];
                    pd[ct >> 1] += v * dwv[ct];
                }
#pragma unroll
                for (int m = 1; m < 16; m <<= 1)
#pragma unroll
                    for (int h = 0; h < 4; h++) {
                        ps[h] += __shfl_xor(ps[h], m);
                        pd[h] += __shfl_xor(pd[h], m);
                    }
                if (gr < M) {
#pragma unroll
                    for (int ct = 0; ct < NCT; ct++)
                        hb[(size_t)gr * BN + ct * 16 + col] = f2bf(acc[rt][ct][r]);
                    if (col == 0) {
                        *(float4*)(a_s + (size_t)gr * 4) = make_float4(ps[0], ps[1], ps[2], ps[3]);
                        *(float4*)(a_d + (size_t)gr * 4) = make_float4(pd[0], pd[1], pd[2], pd[3]);
                    }
                }
            } else {
                float ps = 0.f, pd = 0.f;
#pragma unroll
                for (int ct = 0; ct < NCT; ct++) {
                    float v = acc[rt][ct][r];
                    ps += v * swv[ct];
                    pd += v * dwv[ct];
                }
#pragma unroll
                for (int m = 1; m < 16; m <<= 1) {
                    ps += __shfl_xor(ps, m);
                    pd += __shfl_xor(pd, m);
                }
                if (gr < M) {
#pragma unroll
                    for (int ct = 0; ct < NCT; ct++)
                        hb[(size_t)gr * BN + ct * 16 + col] = f2bf(acc[rt][ct][r]);
                    if (col == 0) { a_s[gr] = ps; a_d[gr] = pd; }
                }
            }
        }
    }
}

// B staging into LDS (stride LDKB), whole Wt (BN x K)
template <int BN>
__device__ __forceinline__ void stage_B(unsigned short* Bs,
                                        const unsigned short* __restrict__ Bt, int K) {
    int tid = threadIdx.x;
    int kvs = (K == 64) ? 3 : 4;
    for (int idx = tid; idx < (BN << kvs); idx += 256) {
        int br = idx >> kvs;
        int ko = (idx & ((1 << kvs) - 1)) << 3;
        *(uint4*)(&Bs[br * LDKB + ko]) = *(const uint4*)(Bt + (size_t)br * K + ko);
    }
}

template <int BN, int H>
__global__ __launch_bounds__(256) void k_mfma_att(
    const unsigned short* __restrict__ Ab, const unsigned short* __restrict__ Bt,
    const float* __restrict__ as_, const float* __restrict__ ad_,
    unsigned short* __restrict__ hb, float* __restrict__ a_s,
    float* __restrict__ a_d, int M, int K) {
    __shared__ unsigned short Bs[128 * LDKB];
    stage_B<BN>(Bs, Bt, K);
    __syncthreads();
    gemm_tile<BN, H>(blockIdx.x * 128, Ab, Bs, as_, ad_, hb, a_s, a_d, M, K);
}

// -------- 4-nodes-per-wave aggregate (R2/R7-verified, single full-range dispatch) --------
__global__ __launch_bounds__(128) void k_aggregate_ln(
    const unsigned short* __restrict__ hb, const float* __restrict__ a_src,
    const float* __restrict__ a_dst, const int* __restrict__ row_ptr,
    const int* __restrict__ esrc, const float* __restrict__ bias,
    const float* __restrict__ gamma, const float* __restrict__ beta,
    unsigned short* __restrict__ xb) {
    __shared__ uint2 slab_all[2][4 * 4 * DCAPP];
    int tid = threadIdx.x;
    int w = tid >> 6, lane = tid & 63;
    int g = lane >> 4, i = lane & 15;
    int myhead = i >> 2;
    uint2* slab = slab_all[w];
    int n0 = blockIdx.x * 8 + w * 4;
    int n = n0 + g;
    bool valid = n < NN;
    int start = 0, deg = 0;
    if (valid) {
        start = row_ptr[n];
        int end = (n == NN - 1) ? ETOT : row_ptr[n + 1];
        deg = end - start;
    }
    int wmax = deg;
#pragma unroll
    for (int m = 1; m < 64; m <<= 1) wmax = max(wmax, __shfl_xor(wmax, m));

    if (wmax <= DCAP) {
        float4 ad = make_float4(0.f, 0.f, 0.f, 0.f);
        if (valid) ad = ((const float4*)a_dst)[n];
        float d0 = 0.f, d1 = 0.f, d2 = 0.f, d3 = 0.f;
        uint2* nslab = slab + g * (4 * DCAPP);
        for (int k = i; k < deg; k += 16) {
            int s = esrc[start + k];
            float4 a = ((const float4*)a_src)[s];
            float e0 = a.x + ad.x; e0 = fmaxf(e0, SLOPE * e0); float x0 = __expf(e0);
            float e1 = a.y + ad.y; e1 = fmaxf(e1, SLOPE * e1); float x1 = __expf(e1);
            float e2 = a.z + ad.z; e2 = fmaxf(e2, SLOPE * e2); float x2 = __expf(e2);
            float e3 = a.w + ad.w; e3 = fmaxf(e3, SLOPE * e3); float x3 = __expf(e3);
            nslab[0 * DCAPP + k] = make_uint2((unsigned)s, __float_as_uint(x0));
            nslab[1 * DCAPP + k] = make_uint2((unsigned)s, __float_as_uint(x1));
            nslab[2 * DCAPP + k] = make_uint2((unsigned)s, __float_as_uint(x2));
            nslab[3 * DCAPP + k] = make_uint2((unsigned)s, __float_as_uint(x3));
            d0 += x0; d1 += x1; d2 += x2; d3 += x3;
        }
#pragma unroll
        for (int m = 1; m < 16; m <<= 1) {
            d0 += __shfl_xor(d0, m);
            d1 += __shfl_xor(d1, m);
            d2 += __shfl_xor(d2, m);
            d3 += __shfl_xor(d3, m);
        }
        float dh = myhead == 0 ? d0 : myhead == 1 ? d1 : myhead == 2 ? d2 : d3;
        float inv = 1.f / (dh + 1e-16f);
        wave_lds_fence();

        float acc[8];
#pragma unroll
        for (int k = 0; k < 8; k++) acc[k] = 0.f;
        const uint2* myrow = nslab + myhead * DCAPP;
        const unsigned short* hbase = hb + i * 8;
        int j = 0;
        for (; j + 4 <= deg; j += 4) {
            uint2 p0 = myrow[j], p1 = myrow[j + 1], p2 = myrow[j + 2], p3 = myrow[j + 3];
            uint4 u0 = *(const uint4*)(hbase + (size_t)p0.x * 128);
            uint4 u1 = *(const uint4*)(hbase + (size_t)p1.x * 128);
            uint4 u2 = *(const uint4*)(hbase + (size_t)p2.x * 128);
            uint4 u3 = *(const uint4*)(hbase + (size_t)p3.x * 128);
            fma8(acc, u0, __uint_as_float(p0.y));
            fma8(acc, u1, __uint_as_float(p1.y));
            fma8(acc, u2, __uint_as_float(p2.y));
            fma8(acc, u3, __uint_as_float(p3.y));
        }
        for (; j < deg; j++) {
            uint2 p = myrow[j];
            uint4 uu = *(const uint4*)(hbase + (size_t)p.x * 128);
            fma8(acc, uu, __uint_as_float(p.y));
        }
#pragma unroll
        for (int k = 0; k < 8; k++) acc[k] *= inv;

        if (valid) {
            float y[8];
            float sum = 0.f;
            const float4* bp = (const float4*)(bias + i * 8);
            float4 b0 = bp[0], b1 = bp[1];
#pragma unroll
            for (int k = 0; k < 8; k++) {
                float b = k < 4 ? (&b0.x)[k] : (&b1.x)[k - 4];
                y[k] = acc[k] + b;
                sum += y[k];
            }
#pragma unroll
            for (int m = 1; m < 16; m <<= 1) sum += __shfl_xor(sum, m);
            float mu = sum * (1.f / 128.f);
            float ss = 0.f;
            float d[8];
#pragma unroll
            for (int k = 0; k < 8; k++) { d[k] = y[k] - mu; ss += d[k] * d[k]; }
#pragma unroll
            for (int m = 1; m < 16; m <<= 1) ss += __shfl_xor(ss, m);
            float is = rsqrtf(ss * (1.f / 128.f) + 1e-5f);
            const float4* gp = (const float4*)(gamma + i * 8);
            const float4* ep = (const float4*)(beta + i * 8);
            float4 g0 = gp[0], g1 = gp[1], e0 = ep[0], e1 = ep[1];
            unsigned short o16[8];
#pragma unroll
            for (int k = 0; k < 8; k++) {
                float gm = k < 4 ? (&g0.x)[k] : (&g1.x)[k - 4];
                float bt = k < 4 ? (&e0.x)[k] : (&e1.x)[k - 4];
                float z = gm * (d[k] * is) + bt;
                o16[k] = f2bf(z > 0.f ? z : __expf(z) - 1.f);
            }
            *(uint4*)(xb + (size_t)n * 128 + i * 8) = *(uint4*)o16;
        }
    } else {
        // cold path (~never): wave's 4 nodes sequentially, full-wave.
        for (int m4 = 0; m4 < 4; m4++) {
            int nm = n0 + m4;
            if (nm >= NN) continue;
            int startm = row_ptr[nm];
            int endm = (nm == NN - 1) ? ETOT : row_ptr[nm + 1];
            int degm = endm - startm;
            float4 ad = ((const float4*)a_dst)[nm];
            int gg = lane >> 4, c16 = lane & 15, hh = c16 >> 2;
            float acc[8];
#pragma unroll
            for (int k = 0; k < 8; k++) acc[k] = 0.f;
            if (degm <= 64) {
                int msrc = 0;
                float me0 = 0.f, me1 = 0.f, me2 = 0.f, me3 = 0.f;
                if (lane < degm) {
                    int s = esrc[startm + lane];
                    msrc = s;
                    float4 a = ((const float4*)a_src)[s];
                    float e0 = a.x + ad.x; e0 = fmaxf(e0, SLOPE * e0); me0 = __expf(e0);
                    float e1 = a.y + ad.y; e1 = fmaxf(e1, SLOPE * e1); me1 = __expf(e1);
                    float e2 = a.z + ad.z; e2 = fmaxf(e2, SLOPE * e2); me2 = __expf(e2);
                    float e3 = a.w + ad.w; e3 = fmaxf(e3, SLOPE * e3); me3 = __expf(e3);
                }
                float d0 = me0, d1 = me1, d2 = me2, d3 = me3;
#pragma unroll
                for (int m = 1; m < 64; m <<= 1) {
                    d0 += __shfl_xor(d0, m);
                    d1 += __shfl_xor(d1, m);
                    d2 += __shfl_xor(d2, m);
                    d3 += __shfl_xor(d3, m);
                }
                me0 *= 1.f / (d0 + 1e-16f);
                me1 *= 1.f / (d1 + 1e-16f);
                me2 *= 1.f / (d2 + 1e-16f);
                me3 *= 1.f / (d3 + 1e-16f);
                int iters = (degm + 3) >> 2;
                for (int it = 0; it < iters; it++) {
                    int j = gg + (it << 2);
                    int jj = j < degm ? j : 0;
                    int s = __shfl(msrc, jj);
                    float a0 = __shfl(me0, jj), a1 = __shfl(me1, jj);
                    float a2 = __shfl(me2, jj), a3 = __shfl(me3, jj);
                    if (j < degm) {
                        float al = hh == 0 ? a0 : hh == 1 ? a1 : hh == 2 ? a2 : a3;
                        uint4 uu = *(const uint4*)(hb + (size_t)s * 128 + c16 * 8);
                        fma8(acc, uu, al);
                    }
                }
            } else {
                float d0 = 0.f, d1 = 0.f, d2 = 0.f, d3 = 0.f;
                for (int k = startm + lane; k < endm; k += 64) {
                    int s = esrc[k];
                    float4 a = ((const float4*)a_src)[s];
                    float e0 = a.x + ad.x; e0 = fmaxf(e0, SLOPE * e0); d0 += __expf(e0);
                    float e1 = a.y + ad.y; e1 = fmaxf(e1, SLOPE * e1); d1 += __expf(e1);
                    float e2 = a.z + ad.z; e2 = fmaxf(e2, SLOPE * e2); d2 += __expf(e2);
                    float e3 = a.w + ad.w; e3 = fmaxf(e3, SLOPE * e3); d3 += __expf(e3);
                }
#pragma unroll
                for (int m = 1; m < 64; m <<= 1) {
                    d0 += __shfl_xor(d0, m);
                    d1 += __shfl_xor(d1, m);
                    d2 += __shfl_xor(d2, m);
                    d3 += __shfl_xor(d3, m);
                }
                float invh = hh == 0 ? 1.f / (d0 + 1e-16f) : hh == 1 ? 1.f / (d1 + 1e-16f)
                           : hh == 2 ? 1.f / (d2 + 1e-16f) : 1.f / (d3 + 1e-16f);
                float adh = hh == 0 ? ad.x : hh == 1 ? ad.y : hh == 2 ? ad.z : ad.w;
                for (int j = gg; j < degm; j += 4) {
                    int s = esrc[startm + j];
                    float e = a_src[(size_t)s * 4 + hh] + adh;
                    e = fmaxf(e, SLOPE * e);
                    float al = __expf(e) * invh;
                    uint4 uu = *(const uint4*)(hb + (size_t)s * 128 + c16 * 8);
                    fma8(acc, uu, al);
                }
            }
#pragma unroll
            for (int k = 0; k < 8; k++) {
                acc[k] += __shfl_xor(acc[k], 16);
                acc[k] += __shfl_xor(acc[k], 32);
            }
            if (lane < 16) {
                float y[8];
                float sum = 0.f;
                const float4* bp = (const float4*)(bias + lane * 8);
                float4 b0 = bp[0], b1 = bp[1];
#pragma unroll
                for (int k = 0; k < 8; k++) {
                    float b = k < 4 ? (&b0.x)[k] : (&b1.x)[k - 4];
                    y[k] = acc[k] + b;
                    sum += y[k];
                }
#pragma unroll
                for (int m = 1; m < 16; m <<= 1) sum += __shfl_xor(sum, m);
                float mu = sum * (1.f / 128.f);
                float ss = 0.f;
                float d[8];
#pragma unroll
                for (int k = 0; k < 8; k++) { d[k] = y[k] - mu; ss += d[k] * d[k]; }
#pragma unroll
                for (int m = 1; m < 16; m <<= 1) ss += __shfl_xor(ss, m);
                float is = rsqrtf(ss * (1.f / 128.f) + 1e-5f);
                const float4* gp = (const float4*)(gamma + lane * 8);
                const float4* ep = (const float4*)(beta + lane * 8);
                float4 g0 = gp[0], g1 = gp[1], e0 = ep[0], e1 = ep[1];
                unsigned short o16[8];
#pragma unroll
                for (int k = 0; k < 8; k++) {
                    float gm = k < 4 ? (&g0.x)[k] : (&g1.x)[k - 4];
                    float bt = k < 4 ? (&e0.x)[k] : (&e1.x)[k - 4];
                    float z = gm * (d[k] * is) + bt;
                    o16[k] = f2bf(z > 0.f ? z : __expf(z) - 1.f);
                }
                *(uint4*)(xb + (size_t)nm * 128 + lane * 8) = *(uint4*)o16;
            }
        }
    }
}

// -------- final layer: 8-lane groups, 8 nodes/wave (R7-verified). H=1, C=32. --------
__global__ __launch_bounds__(128) void k_agg_final(
    const unsigned short* __restrict__ hb, const float* __restrict__ a_src,
    const float* __restrict__ a_dst, const int* __restrict__ row_ptr,
    const int* __restrict__ esrc, const float* __restrict__ bf,
    float* __restrict__ out) {
    __shared__ uint2 slab_all[2][8 * DCAPP];
    int tid = threadIdx.x;
    int w = tid >> 6, lane = tid & 63;
    int g = lane >> 3, i = lane & 7;
    uint2* nslab = slab_all[w] + g * DCAPP;
    int n0 = blockIdx.x * 16 + w * 8;
    int n = n0 + g;
    bool valid = n < NN;
    int start = 0, deg = 0;
    if (valid) {
        start = row_ptr[n];
        int end = (n == NN - 1) ? ETOT : row_ptr[n + 1];
        deg = end - start;
    }
    int wmax = deg;
#pragma unroll
    for (int m = 1; m < 64; m <<= 1) wmax = max(wmax, __shfl_xor(wmax, m));

    if (wmax <= DCAP) {
        float adn = valid ? a_dst[n] : 0.f;
        float d = 0.f;
        for (int k = i; k < deg; k += 8) {
            int s = esrc[start + k];
            float e = a_src[s] + adn;
            e = fmaxf(e, SLOPE * e);
            float xv = __expf(e);
            nslab[k] = make_uint2((unsigned)s, __float_as_uint(xv));
            d += xv;
        }
#pragma unroll
        for (int m = 1; m < 8; m <<= 1) d += __shfl_xor(d, m);
        float inv = 1.f / (d + 1e-16f);
        wave_lds_fence();

        float acc[4] = {0.f, 0.f, 0.f, 0.f};
        const unsigned short* hbase = hb + i * 4;
        int j = 0;
        for (; j + 2 <= deg; j += 2) {
            uint2 p0 = nslab[j], p1 = nslab[j + 1];
            uint2 u0 = *(const uint2*)(hbase + (size_t)p0.x * 32);
            uint2 u1 = *(const uint2*)(hbase + (size_t)p1.x * 32);
            fma4(acc, u0, __uint_as_float(p0.y));
            fma4(acc, u1, __uint_as_float(p1.y));
        }
        if (j < deg) {
            uint2 p = nslab[j];
            uint2 u = *(const uint2*)(hbase + (size_t)p.x * 32);
            fma4(acc, u, __uint_as_float(p.y));
        }
        if (valid) {
            float4 b4 = ((const float4*)bf)[i];
            float4 o = make_float4(acc[0] * inv + b4.x, acc[1] * inv + b4.y,
                                   acc[2] * inv + b4.z, acc[3] * inv + b4.w);
            ((float4*)out)[(size_t)n * 8 + i] = o;
        }
    } else {
        for (int m8 = 0; m8 < 8; m8++) {
            int nm = n0 + m8;
            if (nm >= NN) continue;
            int startm = row_ptr[nm];
            int endm = (nm == NN - 1) ? ETOT : row_ptr[nm + 1];
            int degm = endm - startm;
            float adn = a_dst[nm];
            int gg = lane >> 3, c8 = lane & 7;
            float d = 0.f;
            for (int k = startm + lane; k < endm; k += 64) {
                int s = esrc[k];
                float e = a_src[s] + adn;
                e = fmaxf(e, SLOPE * e);
                d += __expf(e);
            }
#pragma unroll
            for (int m = 1; m < 64; m <<= 1) d += __shfl_xor(d, m);
            float inv = 1.f / (d + 1e-16f);
            float acc[4] = {0.f, 0.f, 0.f, 0.f};
            for (int j = gg; j < degm; j += 8) {
                int s = esrc[startm + j];
                float e = a_src[s] + adn;
                e = fmaxf(e, SLOPE * e);
                float al = __expf(e) * inv;
                uint2 u = *(const uint2*)(hb + (size_t)s * 32 + c8 * 4);
                fma4(acc, u, al);
            }
#pragma unroll
            for (int k = 0; k < 4; k++) {
                acc[k] += __shfl_xor(acc[k], 8);
                acc[k] += __shfl_xor(acc[k], 16);
                acc[k] += __shfl_xor(acc[k], 32);
            }
            if (lane < 8) {
                float4 b4 = ((const float4*)bf)[lane];
                float4 o = make_float4(acc[0] + b4.x, acc[1] + b4.y, acc[2] + b4.z,
                                       acc[3] + b4.w);
                ((float4*)out)[(size_t)nm * 8 + lane] = o;
            }
        }
    }
}

// ---------------- launch ----------------
extern "C" void kernel_launch(void* const* d_in, const int* in_sizes, int n_in,
                              void* d_out, int out_size, void* d_ws,
                              size_t ws_size, hipStream_t stream) {
    const float* x  = (const float*)d_in[0];
    const int* ei   = (const int*)d_in[1];
    const float* W[3]  = {(const float*)d_in[2], (const float*)d_in[8],  (const float*)d_in[14]};
    const float* AS[3] = {(const float*)d_in[3], (const float*)d_in[9],  (const float*)d_in[15]};
    const float* AD[3] = {(const float*)d_in[4], (const float*)d_in[10], (const float*)d_in[16]};
    const float* Bb[3] = {(const float*)d_in[5], (const float*)d_in[11], (const float*)d_in[17]};
    const float* G[3]  = {(const float*)d_in[6], (const float*)d_in[12], (const float*)d_in[18]};
    const float* BE[3] = {(const float*)d_in[7], (const float*)d_in[13], (const float*)d_in[19]};
    const float* Wf  = (const float*)d_in[20];
    const float* asf = (const float*)d_in[21];
    const float* adf = (const float*)d_in[22];
    const float* bfp = (const float*)d_in[23];
    float* out = (float*)d_out;

    unsigned short* xb = (unsigned short*)d_ws;          // NN*128 bf16 (layer0 uses [NN][64])
    unsigned short* hb = xb + (size_t)NN * 128;          // NN*128 bf16
    float* a_s = (float*)(hb + (size_t)NN * 128);
    float* a_d = a_s + (size_t)NN * 4;
    int* row_ptr = (int*)(a_d + (size_t)NN * 4);
    int* esrc    = row_ptr + NN;
    int* gbh     = esrc + ETOT;                          // NB ints
    int* gcur    = gbh + NB;                             // NB ints (adjacent: one memset)
    int* pbuf    = gcur + NB;                            // EE ints
    unsigned short* Wt0 = (unsigned short*)(pbuf + EE);  // 128*64
    unsigned short* Wt1 = Wt0 + 128 * 64;                // 128*128
    unsigned short* Wt2 = Wt1 + 128 * 128;               // 128*128
    unsigned short* Wtf = Wt2 + 128 * 128;               // 32*128

    // zero bucket histogram + bucket cursors (adjacent), then fused prep
    hipMemsetAsync(gbh, 0, 2 * NB * sizeof(int), stream);
    k_prep<<<XB_BLOCKS + WB_BLOCKS + BH_BLOCKS, 256, 0, stream>>>(
        x, xb, W[0], W[1], W[2], Wf, Wt0, Wt1, Wt2, Wtf, gbh, ei);

    // CSR build (scan computed in-LDS per block; k_bscan eliminated)
    k_bscatter<<<(EE + CCH - 1) / CCH, 256, 0, stream>>>(ei, gbh, gcur, pbuf);
    k_bcsr<<<NB, 256, 0, stream>>>(pbuf, gbh, row_ptr, esrc);

    // layers
    const unsigned short* Wts[3] = {Wt0, Wt1, Wt2};
    int K = 64;
    for (int l = 0; l < 3; l++) {
        k_mfma_att<128, 4><<<GBLK, 256, 0, stream>>>(xb, Wts[l], AS[l], AD[l],
                                                     hb, a_s, a_d, NN, K);
        k_aggregate_ln<<<(NN + 7) / 8, 128, 0, stream>>>(hb, a_s, a_d, row_ptr,
                                                         esrc, Bb[l], G[l], BE[l], xb);
        K = 128;
    }
    k_mfma_att<32, 1><<<GBLK, 256, 0, stream>>>(xb, Wtf, asf, adf, hb, a_s, a_d,
                                                NN, 128);
    k_agg_final<<<(NN + 15) / 16, 128, 0, stream>>>(hb, a_s, a_d, row_ptr, esrc,
                                                    bfp, out);
}

// Round 13
// 497.572 us; speedup vs baseline: 1.0725x; 1.0219x over previous
//
#include <hip/hip_runtime.h>
#include <hip/hip_bf16.h>

constexpr int NN   = 100000;
constexpr int EE   = 1600000;
constexpr int ETOT = EE + NN;
constexpr float SLOPE = 0.2f;
constexpr int BSH = 8;      // nodes per bucket = 256
constexpr int NB  = (NN + (1 << BSH) - 1) >> BSH;  // 391 buckets
constexpr int CCH = 8192;   // edges per scatter block
constexpr int DCAP  = 36;   // per-node edge cap for packed path
constexpr int DCAPP = 37;   // padded stride -> phase-B reads conflict-free
constexpr int LDKB  = 136;  // B LDS stride: 128 + 8 pad
constexpr int XB_BLOCKS = (NN * 64 / 8) / 256;     // 3125 exact
constexpr int WB_BLOCKS = 176;
constexpr int BH_BLOCKS = (EE + 2047) / 2048;      // 782 bhist chunks
constexpr int GBLK = (NN + 127) / 128;             // 782 GEMM tiles
constexpr int SCAT_BLOCKS = (EE + CCH - 1) / CCH;  // 196 scatter chunks

typedef __attribute__((ext_vector_type(8))) short short8;
typedef __attribute__((ext_vector_type(4))) float f32x4;

__device__ __forceinline__ float bf_lo(unsigned u) { return __uint_as_float(u << 16); }
__device__ __forceinline__ float bf_hi(unsigned u) { return __uint_as_float(u & 0xffff0000u); }
__device__ __forceinline__ unsigned short f2bf(float f) {
    __hip_bfloat16 h = __float2bfloat16(f);
    return *(unsigned short*)&h;
}
__device__ __forceinline__ void wave_lds_fence() {
    __asm__ volatile("s_waitcnt lgkmcnt(0)" ::: "memory");
}
__device__ __forceinline__ void fma8(float* acc, uint4 u, float al) {
    acc[0] += bf_lo(u.x) * al; acc[1] += bf_hi(u.x) * al;
    acc[2] += bf_lo(u.y) * al; acc[3] += bf_hi(u.y) * al;
    acc[4] += bf_lo(u.z) * al; acc[5] += bf_hi(u.z) * al;
    acc[6] += bf_lo(u.w) * al; acc[7] += bf_hi(u.w) * al;
}
__device__ __forceinline__ void fma4(float* acc, uint2 u, float al) {
    acc[0] += bf_lo(u.x) * al; acc[1] += bf_hi(u.x) * al;
    acc[2] += bf_lo(u.y) * al; acc[3] += bf_hi(u.y) * al;
}

// ---- fused prep: x->bf16, all W->bf16^T, and bucket histogram (gbh pre-zeroed
// by hipMemsetAsync on the same stream) ----
__global__ __launch_bounds__(256) void k_prep(
    const float* __restrict__ x, unsigned short* __restrict__ xb,
    const float* __restrict__ W0, const float* __restrict__ W1,
    const float* __restrict__ W2, const float* __restrict__ Wf,
    unsigned short* __restrict__ Wt0, unsigned short* __restrict__ Wt1,
    unsigned short* __restrict__ Wt2, unsigned short* __restrict__ Wtf,
    int* __restrict__ gbh, const int* __restrict__ ei) {
    int b = blockIdx.x, t = threadIdx.x;
    if (b < XB_BLOCKS) {
        int i = b * 256 + t;
        const float4* xp = (const float4*)(x + (size_t)i * 8);
        float4 v0 = xp[0], v1 = xp[1];
        unsigned short o[8] = {f2bf(v0.x), f2bf(v0.y), f2bf(v0.z), f2bf(v0.w),
                               f2bf(v1.x), f2bf(v1.y), f2bf(v1.z), f2bf(v1.w)};
        *(uint4*)(xb + (size_t)i * 8) = *(uint4*)o;
    } else if (b < XB_BLOCKS + WB_BLOCKS) {
        int i = (b - XB_BLOCKS) * 256 + t;
        if (i < 8192) {                       // W0: 64x128
            int k = i / 128, n = i % 128;
            Wt0[n * 64 + k] = f2bf(W0[i]);
        } else if (i < 24576) {               // W1: 128x128
            int j = i - 8192; int k = j / 128, n = j % 128;
            Wt1[n * 128 + k] = f2bf(W1[j]);
        } else if (i < 40960) {               // W2: 128x128
            int j = i - 24576; int k = j / 128, n = j % 128;
            Wt2[n * 128 + k] = f2bf(W2[j]);
        } else if (i < 45056) {               // Wf: 128x32
            int j = i - 40960; int k = j / 32, n = j % 32;
            Wtf[n * 128 + k] = f2bf(Wf[j]);
        }
    } else {
        // bucket histogram chunk
        __shared__ int h[NB];
        for (int i = t; i < NB; i += 256) h[i] = 0;
        __syncthreads();
        int i = (b - XB_BLOCKS - WB_BLOCKS) * 2048 + t;
#pragma unroll
        for (int k = 0; k < 8; k++, i += 256)
            if (i < EE) atomicAdd(&h[ei[EE + i] >> BSH], 1);
        __syncthreads();
        for (int j = t; j < NB; j += 256)
            if (h[j]) atomicAdd(&gbh[j], h[j]);
    }
}

// ------- GEMM tile body (R6-verified): B pre-staged in LDS, A direct global->VGPR -------
template <int BN, int H>
__device__ __forceinline__ void gemm_tile(
    int rowBase, const unsigned short* __restrict__ Ab,
    const unsigned short* Bs, const float* __restrict__ as_,
    const float* __restrict__ ad_, unsigned short* __restrict__ hb,
    float* __restrict__ a_s, float* __restrict__ a_d, int M, int K) {
    constexpr int NCT = BN / 16;
    int tid = threadIdx.x;
    int lane = tid & 63, w = tid >> 6;
    int q = lane >> 4, col = lane & 15;

    f32x4 acc[2][NCT];
#pragma unroll
    for (int rt = 0; rt < 2; rt++)
#pragma unroll
        for (int ct = 0; ct < NCT; ct++) acc[rt][ct] = (f32x4){0.f, 0.f, 0.f, 0.f};

    int r0 = rowBase + w * 32 + col;
    int grc0 = min(r0, M - 1);
    int grc1 = min(r0 + 16, M - 1);
    const unsigned short* a0p = Ab + (size_t)grc0 * K + q * 8;
    const unsigned short* a1p = Ab + (size_t)grc1 * K + q * 8;

    int nph = K >> 6;
    for (int ph = 0; ph < nph; ph++) {
        int kof = ph * 64;
        short8 af[2][2];
        af[0][0] = *(const short8*)(a0p + kof);
        af[0][1] = *(const short8*)(a0p + kof + 32);
        af[1][0] = *(const short8*)(a1p + kof);
        af[1][1] = *(const short8*)(a1p + kof + 32);
#pragma unroll
        for (int kt = 0; kt < 2; kt++)
#pragma unroll
            for (int ct = 0; ct < NCT; ct++) {
                short8 bf = *(const short8*)(&Bs[(ct * 16 + col) * LDKB + kof + kt * 32 + q * 8]);
#pragma unroll
                for (int rt = 0; rt < 2; rt++)
                    acc[rt][ct] = __builtin_amdgcn_mfma_f32_16x16x32_bf16(
                        af[rt][kt], bf, acc[rt][ct], 0, 0, 0);
            }
    }

    float swv[NCT], dwv[NCT];
#pragma unroll
    for (int ct = 0; ct < NCT; ct++) {
        int c = ct * 16 + col;
        swv[ct] = as_[c];
        dwv[ct] = ad_[c];
    }
#pragma unroll
    for (int rt = 0; rt < 2; rt++) {
#pragma unroll
        for (int r = 0; r < 4; r++) {
            int gr = rowBase + w * 32 + rt * 16 + q * 4 + r;
            if constexpr (H == 4) {
                float ps[4] = {0, 0, 0, 0}, pd[4] = {0, 0, 0, 0};
#pragma unroll
                for (int ct = 0; ct < NCT; ct++) {
                    float v = acc[rt][ct][r];
                    ps[ct >> 1] += v * swv[ct];
                    pd[ct >> 1] += v * dwv[ct];
                }
#pragma unroll
                for (int m = 1; m < 16; m <<= 1)
#pragma unroll
                    for (int h = 0; h < 4; h++) {
                        ps[h] += __shfl_xor(ps[h], m);
                        pd[h] += __shfl_xor(pd[h], m);
                    }
                if (gr < M) {
#pragma unroll
                    for (int ct = 0; ct < NCT; ct++)
                        hb[(size_t)gr * BN + ct * 16 + col] = f2bf(acc[rt][ct][r]);
                    if (col == 0) {
                        *(float4*)(a_s + (size_t)gr * 4) = make_float4(ps[0], ps[1], ps[2], ps[3]);
                        *(float4*)(a_d + (size_t)gr * 4) = make_float4(pd[0], pd[1], pd[2], pd[3]);
                    }
                }
            } else {
                float ps = 0.f, pd = 0.f;
#pragma unroll
                for (int ct = 0; ct < NCT; ct++) {
                    float v = acc[rt][ct][r];
                    ps += v * swv[ct];
                    pd += v * dwv[ct];
                }
#pragma unroll
                for (int m = 1; m < 16; m <<= 1) {
                    ps += __shfl_xor(ps, m);
                    pd += __shfl_xor(pd, m);
                }
                if (gr < M) {
#pragma unroll
                    for (int ct = 0; ct < NCT; ct++)
                        hb[(size_t)gr * BN + ct * 16 + col] = f2bf(acc[rt][ct][r]);
                    if (col == 0) { a_s[gr] = ps; a_d[gr] = pd; }
                }
            }
        }
    }
}

// B staging into LDS (stride LDKB), whole Wt (BN x K)
template <int BN>
__device__ __forceinline__ void stage_B(unsigned short* Bs,
                                        const unsigned short* __restrict__ Bt, int K) {
    int tid = threadIdx.x;
    int kvs = (K == 64) ? 3 : 4;
    for (int idx = tid; idx < (BN << kvs); idx += 256) {
        int br = idx >> kvs;
        int ko = (idx & ((1 << kvs) - 1)) << 3;
        *(uint4*)(&Bs[br * LDKB + ko]) = *(const uint4*)(Bt + (size_t)br * K + ko);
    }
}

// ------- R13: merged edge-scatter + layer-0 GEMM (mutually independent; both only
// depend on k_prep). Blocks [0,SCAT_BLOCKS) = scatter, rest = GEMM0. Saves one
// dispatch ramp/drain boundary (~10us measured marginal cost, R10).
__global__ __launch_bounds__(256) void k_bsc_gemm0(
    const int* __restrict__ ei, const int* __restrict__ gbh,
    int* __restrict__ gcur, int* __restrict__ pbuf,
    const unsigned short* __restrict__ Ab, const unsigned short* __restrict__ Bt,
    const float* __restrict__ as_, const float* __restrict__ ad_,
    unsigned short* __restrict__ hb, float* __restrict__ a_s,
    float* __restrict__ a_d) {
    __shared__ union U {
        struct { int h[NB], base[NB], cur[NB], sb[512]; } s;
        unsigned short Bs[128 * LDKB];
        __device__ U() {}
    } u;
    int blk = blockIdx.x, t = threadIdx.x;
    if (blk < SCAT_BLOCKS) {
        // ---- bscatter body (R12-verified: in-LDS scan of gbh) ----
        for (int i = t; i < NB; i += 256) { u.s.h[i] = 0; u.s.cur[i] = 0; }
        u.s.sb[t] = (t < NB) ? gbh[t] : 0;
        u.s.sb[t + 256] = (t + 256 < NB) ? gbh[t + 256] : 0;
        __syncthreads();
        for (int off = 1; off < 512; off <<= 1) {
            int x0 = (t >= off) ? u.s.sb[t - off] : 0;
            int x1 = u.s.sb[t + 256 - off];
            __syncthreads();
            u.s.sb[t] += x0; u.s.sb[t + 256] += x1;
            __syncthreads();
        }
        int c0 = blk * CCH;
        int cend = c0 + CCH < EE ? c0 + CCH : EE;
        for (int i = c0 + t; i < cend; i += 256)
            atomicAdd(&u.s.h[ei[EE + i] >> BSH], 1);
        __syncthreads();
        for (int i = t; i < NB; i += 256)
            if (u.s.h[i] > 0)
                u.s.base[i] = ((i > 0) ? u.s.sb[i - 1] : 0) + atomicAdd(&gcur[i], u.s.h[i]);
        __syncthreads();
        for (int i = c0 + t; i < cend; i += 256) {
            int s = ei[i], d = ei[EE + i];
            int b = d >> BSH;
            int c = atomicAdd(&u.s.cur[b], 1);
            pbuf[u.s.base[b] + c] = s | ((d & ((1 << BSH) - 1)) << 17);
        }
    } else {
        // ---- layer-0 GEMM tile (K=64, BN=128) ----
        stage_B<128>(u.Bs, Bt, 64);
        __syncthreads();
        gemm_tile<128, 4>((blk - SCAT_BLOCKS) * 128, Ab, u.Bs, as_, ad_,
                          hb, a_s, a_d, NN, 64);
    }
}

// ---- bcsr (R12-verified: in-LDS scan of gbh for bucket bounds) ----
__global__ __launch_bounds__(256) void k_bcsr(const int* __restrict__ pbuf,
                                              const int* __restrict__ gbh,
                                              int* __restrict__ row_ptr,
                                              int* __restrict__ esrc) {
    constexpr int BNODES = 1 << BSH;
    __shared__ int hist[BNODES];
    __shared__ int cur[BNODES];
    __shared__ int sd[256];
    __shared__ int sb[512];
    int b = blockIdx.x, t = threadIdx.x;
    int node0 = b << BSH;
    hist[t] = 0; cur[t] = 0;
    sb[t] = (t < NB) ? gbh[t] : 0;
    sb[t + 256] = (t + 256 < NB) ? gbh[t + 256] : 0;
    __syncthreads();
    for (int off = 1; off < 512; off <<= 1) {
        int x0 = (t >= off) ? sb[t - off] : 0;
        int x1 = sb[t + 256 - off];
        __syncthreads();
        sb[t] += x0; sb[t + 256] += x1;
        __syncthreads();
    }
    int e0 = (b > 0) ? sb[b - 1] : 0;
    int e1 = sb[b];
    for (int i = e0 + t; i < e1; i += 256)
        atomicAdd(&hist[pbuf[i] >> 17], 1);
    __syncthreads();
    int ts = hist[t];
    sd[t] = ts;
    __syncthreads();
    for (int off = 1; off < 256; off <<= 1) {
        int x = (t >= off) ? sd[t - off] : 0;
        __syncthreads();
        sd[t] += x;
        __syncthreads();
    }
    int ex = sd[t] - ts;
    __syncthreads();
    hist[t] = ex;
    __syncthreads();
    int rbase = e0 + node0;
    int n = node0 + t;
    if (n < NN) {
        int rp = rbase + hist[t] + t;
        row_ptr[n] = rp;
        esrc[rp] = n;  // self loop in slot 0
    }
    __syncthreads();
    for (int i = e0 + t; i < e1; i += 256) {
        int p = pbuf[i];
        int nl = p >> 17;
        int c = atomicAdd(&cur[nl], 1);
        esrc[rbase + hist[nl] + nl + 1 + c] = p & 0x1FFFF;
    }
}

template <int BN, int H>
__global__ __launch_bounds__(256) void k_mfma_att(
    const unsigned short* __restrict__ Ab, const unsigned short* __restrict__ Bt,
    const float* __restrict__ as_, const float* __restrict__ ad_,
    unsigned short* __restrict__ hb, float* __restrict__ a_s,
    float* __restrict__ a_d, int M, int K) {
    __shared__ unsigned short Bs[128 * LDKB];
    stage_B<BN>(Bs, Bt, K);
    __syncthreads();
    gemm_tile<BN, H>(blockIdx.x * 128, Ab, Bs, as_, ad_, hb, a_s, a_d, M, K);
}

// -------- 4-nodes-per-wave aggregate (R2/R7-verified) --------
__global__ __launch_bounds__(128) void k_aggregate_ln(
    const unsigned short* __restrict__ hb, const float* __restrict__ a_src,
    const float* __restrict__ a_dst, const int* __restrict__ row_ptr,
    const int* __restrict__ esrc, const float* __restrict__ bias,
    const float* __restrict__ gamma, const float* __restrict__ beta,
    unsigned short* __restrict__ xb) {
    __shared__ uint2 slab_all[2][4 * 4 * DCAPP];
    int tid = threadIdx.x;
    int w = tid >> 6, lane = tid & 63;
    int g = lane >> 4, i = lane & 15;
    int myhead = i >> 2;
    uint2* slab = slab_all[w];
    int n0 = blockIdx.x * 8 + w * 4;
    int n = n0 + g;
    bool valid = n < NN;
    int start = 0, deg = 0;
    if (valid) {
        start = row_ptr[n];
        int end = (n == NN - 1) ? ETOT : row_ptr[n + 1];
        deg = end - start;
    }
    int wmax = deg;
#pragma unroll
    for (int m = 1; m < 64; m <<= 1) wmax = max(wmax, __shfl_xor(wmax, m));

    if (wmax <= DCAP) {
        float4 ad = make_float4(0.f, 0.f, 0.f, 0.f);
        if (valid) ad = ((const float4*)a_dst)[n];
        float d0 = 0.f, d1 = 0.f, d2 = 0.f, d3 = 0.f;
        uint2* nslab = slab + g * (4 * DCAPP);
        for (int k = i; k < deg; k += 16) {
            int s = esrc[start + k];
            float4 a = ((const float4*)a_src)[s];
            float e0 = a.x + ad.x; e0 = fmaxf(e0, SLOPE * e0); float x0 = __expf(e0);
            float e1 = a.y + ad.y; e1 = fmaxf(e1, SLOPE * e1); float x1 = __expf(e1);
            float e2 = a.z + ad.z; e2 = fmaxf(e2, SLOPE * e2); float x2 = __expf(e2);
            float e3 = a.w + ad.w; e3 = fmaxf(e3, SLOPE * e3); float x3 = __expf(e3);
            nslab[0 * DCAPP + k] = make_uint2((unsigned)s, __float_as_uint(x0));
            nslab[1 * DCAPP + k] = make_uint2((unsigned)s, __float_as_uint(x1));
            nslab[2 * DCAPP + k] = make_uint2((unsigned)s, __float_as_uint(x2));
            nslab[3 * DCAPP + k] = make_uint2((unsigned)s, __float_as_uint(x3));
            d0 += x0; d1 += x1; d2 += x2; d3 += x3;
        }
#pragma unroll
        for (int m = 1; m < 16; m <<= 1) {
            d0 += __shfl_xor(d0, m);
            d1 += __shfl_xor(d1, m);
            d2 += __shfl_xor(d2, m);
            d3 += __shfl_xor(d3, m);
        }
        float dh = myhead == 0 ? d0 : myhead == 1 ? d1 : myhead == 2 ? d2 : d3;
        float inv = 1.f / (dh + 1e-16f);
        wave_lds_fence();

        float acc[8];
#pragma unroll
        for (int k = 0; k < 8; k++) acc[k] = 0.f;
        const uint2* myrow = nslab + myhead * DCAPP;
        const unsigned short* hbase = hb + i * 8;
        int j = 0;
        for (; j + 4 <= deg; j += 4) {
            uint2 p0 = myrow[j], p1 = myrow[j + 1], p2 = myrow[j + 2], p3 = myrow[j + 3];
            uint4 u0 = *(const uint4*)(hbase + (size_t)p0.x * 128);
            uint4 u1 = *(const uint4*)(hbase + (size_t)p1.x * 128);
            uint4 u2 = *(const uint4*)(hbase + (size_t)p2.x * 128);
            uint4 u3 = *(const uint4*)(hbase + (size_t)p3.x * 128);
            fma8(acc, u0, __uint_as_float(p0.y));
            fma8(acc, u1, __uint_as_float(p1.y));
            fma8(acc, u2, __uint_as_float(p2.y));
            fma8(acc, u3, __uint_as_float(p3.y));
        }
        for (; j < deg; j++) {
            uint2 p = myrow[j];
            uint4 uu = *(const uint4*)(hbase + (size_t)p.x * 128);
            fma8(acc, uu, __uint_as_float(p.y));
        }
#pragma unroll
        for (int k = 0; k < 8; k++) acc[k] *= inv;

        if (valid) {
            float y[8];
            float sum = 0.f;
            const float4* bp = (const float4*)(bias + i * 8);
            float4 b0 = bp[0], b1 = bp[1];
#pragma unroll
            for (int k = 0; k < 8; k++) {
                float b = k < 4 ? (&b0.x)[k] : (&b1.x)[k - 4];
                y[k] = acc[k] + b;
                sum += y[k];
            }
#pragma unroll
            for (int m = 1; m < 16; m <<= 1) sum += __shfl_xor(sum, m);
            float mu = sum * (1.f / 128.f);
            float ss = 0.f;
            float d[8];
#pragma unroll
            for (int k = 0; k < 8; k++) { d[k] = y[k] - mu; ss += d[k] * d[k]; }
#pragma unroll
            for (int m = 1; m < 16; m <<= 1) ss += __shfl_xor(ss, m);
            float is = rsqrtf(ss * (1.f / 128.f) + 1e-5f);
            const float4* gp = (const float4*)(gamma + i * 8);
            const float4* ep = (const float4*)(beta + i * 8);
            float4 g0 = gp[0], g1 = gp[1], e0 = ep[0], e1 = ep[1];
            unsigned short o16[8];
#pragma unroll
            for (int k = 0; k < 8; k++) {
                float gm = k < 4 ? (&g0.x)[k] : (&g1.x)[k - 4];
                float bt = k < 4 ? (&e0.x)[k] : (&e1.x)[k - 4];
                float z = gm * (d[k] * is) + bt;
                o16[k] = f2bf(z > 0.f ? z : __expf(z) - 1.f);
            }
            *(uint4*)(xb + (size_t)n * 128 + i * 8) = *(uint4*)o16;
        }
    } else {
        // cold path (~never): wave's 4 nodes sequentially, full-wave.
        for (int m4 = 0; m4 < 4; m4++) {
            int nm = n0 + m4;
            if (nm >= NN) continue;
            int startm = row_ptr[nm];
            int endm = (nm == NN - 1) ? ETOT : row_ptr[nm + 1];
            int degm = endm - startm;
            float4 ad = ((const float4*)a_dst)[nm];
            int gg = lane >> 4, c16 = lane & 15, hh = c16 >> 2;
            float acc[8];
#pragma unroll
            for (int k = 0; k < 8; k++) acc[k] = 0.f;
            if (degm <= 64) {
                int msrc = 0;
                float me0 = 0.f, me1 = 0.f, me2 = 0.f, me3 = 0.f;
                if (lane < degm) {
                    int s = esrc[startm + lane];
                    msrc = s;
                    float4 a = ((const float4*)a_src)[s];
                    float e0 = a.x + ad.x; e0 = fmaxf(e0, SLOPE * e0); me0 = __expf(e0);
                    float e1 = a.y + ad.y; e1 = fmaxf(e1, SLOPE * e1); me1 = __expf(e1);
                    float e2 = a.z + ad.z; e2 = fmaxf(e2, SLOPE * e2); me2 = __expf(e2);
                    float e3 = a.w + ad.w; e3 = fmaxf(e3, SLOPE * e3); me3 = __expf(e3);
                }
                float d0 = me0, d1 = me1, d2 = me2, d3 = me3;
#pragma unroll
                for (int m = 1; m < 64; m <<= 1) {
                    d0 += __shfl_xor(d0, m);
                    d1 += __shfl_xor(d1, m);
                    d2 += __shfl_xor(d2, m);
                    d3 += __shfl_xor(d3, m);
                }
                me0 *= 1.f / (d0 + 1e-16f);
                me1 *= 1.f / (d1 + 1e-16f);
                me2 *= 1.f / (d2 + 1e-16f);
                me3 *= 1.f / (d3 + 1e-16f);
                int iters = (degm + 3) >> 2;
                for (int it = 0; it < iters; it++) {
                    int j = gg + (it << 2);
                    int jj = j < degm ? j : 0;
                    int s = __shfl(msrc, jj);
                    float a0 = __shfl(me0, jj), a1 = __shfl(me1, jj);
                    float a2 = __shfl(me2, jj), a3 = __shfl(me3, jj);
                    if (j < degm) {
                        float al = hh == 0 ? a0 : hh == 1 ? a1 : hh == 2 ? a2 : a3;
                        uint4 uu = *(const uint4*)(hb + (size_t)s * 128 + c16 * 8);
                        fma8(acc, uu, al);
                    }
                }
            } else {
                float d0 = 0.f, d1 = 0.f, d2 = 0.f, d3 = 0.f;
                for (int k = startm + lane; k < endm; k += 64) {
                    int s = esrc[k];
                    float4 a = ((const float4*)a_src)[s];
                    float e0 = a.x + ad.x; e0 = fmaxf(e0, SLOPE * e0); d0 += __expf(e0);
                    float e1 = a.y + ad.y; e1 = fmaxf(e1, SLOPE * e1); d1 += __expf(e1);
                    float e2 = a.z + ad.z; e2 = fmaxf(e2, SLOPE * e2); d2 += __expf(e2);
                    float e3 = a.w + ad.w; e3 = fmaxf(e3, SLOPE * e3); d3 += __expf(e3);
                }
#pragma unroll
                for (int m = 1; m < 64; m <<= 1) {
                    d0 += __shfl_xor(d0, m);
                    d1 += __shfl_xor(d1, m);
                    d2 += __shfl_xor(d2, m);
                    d3 += __shfl_xor(d3, m);
                }
                float invh = hh == 0 ? 1.f / (d0 + 1e-16f) : hh == 1 ? 1.f / (d1 + 1e-16f)
                           : hh == 2 ? 1.f / (d2 + 1e-16f) : 1.f / (d3 + 1e-16f);
                float adh = hh == 0 ? ad.x : hh == 1 ? ad.y : hh == 2 ? ad.z : ad.w;
                for (int j = gg; j < degm; j += 4) {
                    int s = esrc[startm + j];
                    float e = a_src[(size_t)s * 4 + hh] + adh;
                    e = fmaxf(e, SLOPE * e);
                    float al = __expf(e) * invh;
                    uint4 uu = *(const uint4*)(hb + (size_t)s * 128 + c16 * 8);
                    fma8(acc, uu, al);
                }
            }
#pragma unroll
            for (int k = 0; k < 8; k++) {
                acc[k] += __shfl_xor(acc[k], 16);
                acc[k] += __shfl_xor(acc[k], 32);
            }
            if (lane < 16) {
                float y[8];
                float sum = 0.f;
                const float4* bp = (const float4*)(bias + lane * 8);
                float4 b0 = bp[0], b1 = bp[1];
#pragma unroll
                for (int k = 0; k < 8; k++) {
                    float b = k < 4 ? (&b0.x)[k] : (&b1.x)[k - 4];
                    y[k] = acc[k] + b;
                    sum += y[k];
                }
#pragma unroll
                for (int m = 1; m < 16; m <<= 1) sum += __shfl_xor(sum, m);
                float mu = sum * (1.f / 128.f);
                float ss = 0.f;
                float d[8];
#pragma unroll
                for (int k = 0; k < 8; k++) { d[k] = y[k] - mu; ss += d[k] * d[k]; }
#pragma unroll
                for (int m = 1; m < 16; m <<= 1) ss += __shfl_xor(ss, m);
                float is = rsqrtf(ss * (1.f / 128.f) + 1e-5f);
                const float4* gp = (const float4*)(gamma + lane * 8);
                const float4* ep = (const float4*)(beta + lane * 8);
                float4 g0 = gp[0], g1 = gp[1], e0 = ep[0], e1 = ep[1];
                unsigned short o16[8];
#pragma unroll
                for (int k = 0; k < 8; k++) {
                    float gm = k < 4 ? (&g0.x)[k] : (&g1.x)[k - 4];
                    float bt = k < 4 ? (&e0.x)[k] : (&e1.x)[k - 4];
                    float z = gm * (d[k] * is) + bt;
                    o16[k] = f2bf(z > 0.f ? z : __expf(z) - 1.f);
                }
                *(uint4*)(xb + (size_t)nm * 128 + lane * 8) = *(uint4*)o16;
            }
        }
    }
}

// -------- final layer: 8-lane groups, 8 nodes/wave (R7-verified). H=1, C=32. --------
__global__ __launch_bounds__(128) void k_agg_final(
    const unsigned short* __restrict__ hb, const float* __restrict__ a_src,
    const float* __restrict__ a_dst, const int* __restrict__ row_ptr,
    const int* __restrict__ esrc, const float* __restrict__ bf,
    float* __restrict__ out) {
    __shared__ uint2 slab_all[2][8 * DCAPP];
    int tid = threadIdx.x;
    int w = tid >> 6, lane = tid & 63;
    int g = lane >> 3, i = lane & 7;
    uint2* nslab = slab_all[w] + g * DCAPP;
    int n0 = blockIdx.x * 16 + w * 8;
    int n = n0 + g;
    bool valid = n < NN;
    int start = 0, deg = 0;
    if (valid) {
        start = row_ptr[n];
        int end = (n == NN - 1) ? ETOT : row_ptr[n + 1];
        deg = end - start;
    }
    int wmax = deg;
#pragma unroll
    for (int m = 1; m < 64; m <<= 1) wmax = max(wmax, __shfl_xor(wmax, m));

    if (wmax <= DCAP) {
        float adn = valid ? a_dst[n] : 0.f;
        float d = 0.f;
        for (int k = i; k < deg; k += 8) {
            int s = esrc[start + k];
            float e = a_src[s] + adn;
            e = fmaxf(e, SLOPE * e);
            float xv = __expf(e);
            nslab[k] = make_uint2((unsigned)s, __float_as_uint(xv));
            d += xv;
        }
#pragma unroll
        for (int m = 1; m < 8; m <<= 1) d += __shfl_xor(d, m);
        float inv = 1.f / (d + 1e-16f);
        wave_lds_fence();

        float acc[4] = {0.f, 0.f, 0.f, 0.f};
        const unsigned short* hbase = hb + i * 4;
        int j = 0;
        for (; j + 2 <= deg; j += 2) {
            uint2 p0 = nslab[j], p1 = nslab[j + 1];
            uint2 u0 = *(const uint2*)(hbase + (size_t)p0.x * 32);
            uint2 u1 = *(const uint2*)(hbase + (size_t)p1.x * 32);
            fma4(acc, u0, __uint_as_float(p0.y));
            fma4(acc, u1, __uint_as_float(p1.y));
        }
        if (j < deg) {
            uint2 p = nslab[j];
            uint2 u = *(const uint2*)(hbase + (size_t)p.x * 32);
            fma4(acc, u, __uint_as_float(p.y));
        }
        if (valid) {
            float4 b4 = ((const float4*)bf)[i];
            float4 o = make_float4(acc[0] * inv + b4.x, acc[1] * inv + b4.y,
                                   acc[2] * inv + b4.z, acc[3] * inv + b4.w);
            ((float4*)out)[(size_t)n * 8 + i] = o;
        }
    } else {
        for (int m8 = 0; m8 < 8; m8++) {
            int nm = n0 + m8;
            if (nm >= NN) continue;
            int startm = row_ptr[nm];
            int endm = (nm == NN - 1) ? ETOT : row_ptr[nm + 1];
            int degm = endm - startm;
            float adn = a_dst[nm];
            int gg = lane >> 3, c8 = lane & 7;
            float d = 0.f;
            for (int k = startm + lane; k < endm; k += 64) {
                int s = esrc[k];
                float e = a_src[s] + adn;
                e = fmaxf(e, SLOPE * e);
                d += __expf(e);
            }
#pragma unroll
            for (int m = 1; m < 64; m <<= 1) d += __shfl_xor(d, m);
            float inv = 1.f / (d + 1e-16f);
            float acc[4] = {0.f, 0.f, 0.f, 0.f};
            for (int j = gg; j < degm; j += 8) {
                int s = esrc[startm + j];
                float e = a_src[s] + adn;
                e = fmaxf(e, SLOPE * e);
                float al = __expf(e) * inv;
                uint2 u = *(const uint2*)(hb + (size_t)s * 32 + c8 * 4);
                fma4(acc, u, al);
            }
#pragma unroll
            for (int k = 0; k < 4; k++) {
                acc[k] += __shfl_xor(acc[k], 8);
                acc[k] += __shfl_xor(acc[k], 16);
                acc[k] += __shfl_xor(acc[k], 32);
            }
            if (lane < 8) {
                float4 b4 = ((const float4*)bf)[lane];
                float4 o = make_float4(acc[0] + b4.x, acc[1] + b4.y, acc[2] + b4.z,
                                       acc[3] + b4.w);
                ((float4*)out)[(size_t)nm * 8 + lane] = o;
            }
        }
    }
}

// ---------------- launch ----------------
extern "C" void kernel_launch(void* const* d_in, const int* in_sizes, int n_in,
                              void* d_out, int out_size, void* d_ws,
                              size_t ws_size, hipStream_t stream) {
    const float* x  = (const float*)d_in[0];
    const int* ei   = (const int*)d_in[1];
    const float* W[3]  = {(const float*)d_in[2], (const float*)d_in[8],  (const float*)d_in[14]};
    const float* AS[3] = {(const float*)d_in[3], (const float*)d_in[9],  (const float*)d_in[15]};
    const float* AD[3] = {(const float*)d_in[4], (const float*)d_in[10], (const float*)d_in[16]};
    const float* Bb[3] = {(const float*)d_in[5], (const float*)d_in[11], (const float*)d_in[17]};
    const float* G[3]  = {(const float*)d_in[6], (const float*)d_in[12], (const float*)d_in[18]};
    const float* BE[3] = {(const float*)d_in[7], (const float*)d_in[13], (const float*)d_in[19]};
    const float* Wf  = (const float*)d_in[20];
    const float* asf = (const float*)d_in[21];
    const float* adf = (const float*)d_in[22];
    const float* bfp = (const float*)d_in[23];
    float* out = (float*)d_out;

    unsigned short* xb = (unsigned short*)d_ws;          // NN*128 bf16 (layer0 uses [NN][64])
    unsigned short* hb = xb + (size_t)NN * 128;          // NN*128 bf16
    float* a_s = (float*)(hb + (size_t)NN * 128);
    float* a_d = a_s + (size_t)NN * 4;
    int* row_ptr = (int*)(a_d + (size_t)NN * 4);
    int* esrc    = row_ptr + NN;
    int* gbh     = esrc + ETOT;                          // NB ints
    int* gcur    = gbh + NB;                             // NB ints (adjacent: one memset)
    int* pbuf    = gcur + NB;                            // EE ints
    unsigned short* Wt0 = (unsigned short*)(pbuf + EE);  // 128*64
    unsigned short* Wt1 = Wt0 + 128 * 64;                // 128*128
    unsigned short* Wt2 = Wt1 + 128 * 128;               // 128*128
    unsigned short* Wtf = Wt2 + 128 * 128;               // 32*128

    // zero bucket histogram + bucket cursors (adjacent), then fused prep
    hipMemsetAsync(gbh, 0, 2 * NB * sizeof(int), stream);
    k_prep<<<XB_BLOCKS + WB_BLOCKS + BH_BLOCKS, 256, 0, stream>>>(
        x, xb, W[0], W[1], W[2], Wf, Wt0, Wt1, Wt2, Wtf, gbh, ei);

    // merged: edge scatter + layer-0 GEMM (independent children of k_prep)
    k_bsc_gemm0<<<SCAT_BLOCKS + GBLK, 256, 0, stream>>>(
        ei, gbh, gcur, pbuf, xb, Wt0, AS[0], AD[0], hb, a_s, a_d);
    k_bcsr<<<NB, 256, 0, stream>>>(pbuf, gbh, row_ptr, esrc);
    k_aggregate_ln<<<(NN + 7) / 8, 128, 0, stream>>>(hb, a_s, a_d, row_ptr,
                                                     esrc, Bb[0], G[0], BE[0], xb);

    // layers 1,2
    const unsigned short* Wts[3] = {Wt0, Wt1, Wt2};
    for (int l = 1; l < 3; l++) {
        k_mfma_att<128, 4><<<GBLK, 256, 0, stream>>>(xb, Wts[l], AS[l], AD[l],
                                                     hb, a_s, a_d, NN, 128);
        k_aggregate_ln<<<(NN + 7) / 8, 128, 0, stream>>>(hb, a_s, a_d, row_ptr,
                                                         esrc, Bb[l], G[l], BE[l], xb);
    }
    k_mfma_att<32, 1><<<GBLK, 256, 0, stream>>>(xb, Wtf, asf, adf, hb, a_s, a_d,
                                                NN, 128);
    k_agg_final<<<(NN + 15) / 16, 128, 0, stream>>>(hb, a_s, a_d, row_ptr, esrc,
                                                    bfp, out);
}